// Round 1
// 2199.509 us; speedup vs baseline: 1.3133x; 1.3133x over previous
//
#include <hip/hip_runtime.h>
#include <hip/hip_bf16.h>
#include <cmath>

// ---------------------------------------------------------------------------
// Model dims: H=256 HID=128 V=50000 LV=200 N=512 L=64 M=64 C=4 T=8 K=8
// NOTE (round 5 lesson): cooperative grid.sync() costs ~37us on MI355X —
// never use it for a 126-sync loop; per-step kernel launches (~2-3us) win.
// NOTE (this round): big GEMMs (32768x256x{768,1024}) moved from fp32 VALU
// (64 TF, MfmaUtil=0) to bf16 MFMA 16x16x32, m97-style 128x128 tile with
// global_load_lds(16B) staging. A/B fragments use the SAME lane-group->k
// mapping (k = (lane>>4)*8 + j) so any k-permutation cancels; C/D layout is
// the HW-verified col=lane&15, row=(lane>>4)*4+reg.
// ---------------------------------------------------------------------------

__device__ __forceinline__ float sigf(float x) { return 1.f / (1.f + expf(-x)); }
__device__ __forceinline__ float b2f(__hip_bfloat16 x) { return __bfloat162float(x); }

typedef __attribute__((ext_vector_type(8))) short bf16x8v;  // 8 bf16 (4 VGPRs)
typedef __attribute__((ext_vector_type(4))) float f32x4;

__device__ __forceinline__ void gload16(const __hip_bfloat16* g, __hip_bfloat16* l) {
  __builtin_amdgcn_global_load_lds((const __attribute__((address_space(1))) void*)g,
                                   (__attribute__((address_space(3))) void*)l, 16, 0, 0);
}

// ---------------------------------------------------------------------------
// WXALL weights: [wiou (768) | wf (256)] rows x 256, bias [biou | bf]
// ---------------------------------------------------------------------------
__global__ __launch_bounds__(256) void k_build_wx(const float* __restrict__ wiou,
                                                  const float* __restrict__ wf,
                                                  const float* __restrict__ biou,
                                                  const float* __restrict__ bf,
                                                  float* __restrict__ w,
                                                  float* __restrict__ b) {
  int i = blockIdx.x * 256 + threadIdx.x;
  if (i < 1024 * 256) {
    int j = i >> 8, k = i & 255;
    w[i] = (j < 768) ? wiou[j * 256 + k] : wf[(j - 768) * 256 + k];
  }
  if (i < 1024) b[i] = (i < 768) ? biou[i] : bf[i - 768];
}

// WPROJ: [uiou (768) | uf (256)] rows x 256
__global__ __launch_bounds__(256) void k_build_wproj(const float* __restrict__ uiou,
                                                     const float* __restrict__ uf,
                                                     float* __restrict__ w) {
  int i = blockIdx.x * 256 + threadIdx.x;
  if (i >= 1024 * 256) return;
  int j = i >> 8, k = i & 255;
  w[i] = (j < 768) ? uiou[j * 256 + k] : uf[(j - 768) * 256 + k];
}

__global__ __launch_bounds__(256) void k_zero_misc(float* __restrict__ nei_sum,
                                                   int* __restrict__ deg,
                                                   int* __restrict__ flag) {
  int i = blockIdx.x * 256 + threadIdx.x;
  if (i < 512 * 256) nei_sum[i] = 0.f;
  if (i < 512) deg[i] = 0;
  if (i == 0) *flag = 0;
}

// bool-mask dtype detector (int32 vs byte-packed)
__global__ __launch_bounds__(256) void k_mask_detect(const unsigned* __restrict__ raw,
                                                     int* __restrict__ flag) {
  int i = blockIdx.x * 256 + threadIdx.x;
  if (i < 32768) {
    if (raw[i] > 1u) atomicOr(flag, 1);
  }
}

__global__ __launch_bounds__(256) void k_mask_convert(const void* __restrict__ raw,
                                                      const int* __restrict__ flag,
                                                      int* __restrict__ msk) {
  int i = blockIdx.x * 256 + threadIdx.x;
  if (i >= 512 * 64 * 4) return;
  int v;
  if (*flag) v = ((const unsigned char*)raw)[i] != 0;
  else       v = ((const int*)raw)[i] != 0;
  msk[i] = v;
}

// ---------------------------------------------------------------------------
// fp32 -> bf16 row gather/convert: out[r][0:256] = bf16(A[(ridx?ridx[r]:r)*rstride + 0:256])
// one block = 8 rows; K fixed at 256.
// ---------------------------------------------------------------------------
__global__ __launch_bounds__(256) void k_cvt_bf16(const float* __restrict__ A,
                                                  const int* __restrict__ ridx,
                                                  int rstride,
                                                  __hip_bfloat16* __restrict__ out) {
  int r = blockIdx.x * 8 + (threadIdx.x >> 5);
  int k = (threadIdx.x & 31) * 8;
  const float* src = A + (size_t)(ridx ? ridx[r] : r) * rstride + k;
  float4 v0 = *(const float4*)src;
  float4 v1 = *(const float4*)(src + 4);
  union { ushort4 u; __hip_bfloat16 b[4]; } p0, p1;
  p0.b[0] = __float2bfloat16(v0.x); p0.b[1] = __float2bfloat16(v0.y);
  p0.b[2] = __float2bfloat16(v0.z); p0.b[3] = __float2bfloat16(v0.w);
  p1.b[0] = __float2bfloat16(v1.x); p1.b[1] = __float2bfloat16(v1.y);
  p1.b[2] = __float2bfloat16(v1.z); p1.b[3] = __float2bfloat16(v1.w);
  __hip_bfloat16* dst = out + (size_t)r * 256 + k;
  *(ushort4*)dst = p0.u;
  *(ushort4*)(dst + 4) = p1.u;
}

// ---------------------------------------------------------------------------
// bf16 MFMA GEMM: C[R x J] = A[R x K] @ W[J x K]^T (+bias, relu opt).
// 128x128 tile, BK=32, 256 threads = 4 waves in 2x2, each wave 64x64 out
// (4x4 fragments of 16x16x32). global_load_lds width-16 staging, linear LDS.
// Requires R%128==0, J%128==0, K%32==0.
// ---------------------------------------------------------------------------
__global__ __launch_bounds__(256) void k_gemm_mfma(const __hip_bfloat16* __restrict__ A,
                                                   const __hip_bfloat16* __restrict__ W,
                                                   const float* __restrict__ bias,
                                                   void* __restrict__ Cv,
                                                   int R, int K, int J,
                                                   int relu, int out_bf16) {
  __shared__ __align__(16) __hip_bfloat16 As[128 * 32];
  __shared__ __align__(16) __hip_bfloat16 Bs[128 * 32];
  int njt = J >> 7;
  int rt = blockIdx.x / njt;
  int jt = blockIdx.x - rt * njt;
  int tid = threadIdx.x;
  int w = tid >> 6, lane = tid & 63;
  int wr = w >> 1, wc = w & 1;

  // staging: each wave stages rows [w*32, w*32+32) of both tiles, 2 chunks of
  // 16 rows; lane l covers row w*32 + q*16 + (l>>2), k-bytes (l&3)*16.
  const __hip_bfloat16* ga = A + (size_t)(rt * 128 + w * 32 + (lane >> 2)) * K + (lane & 3) * 8;
  const __hip_bfloat16* gb = W + (size_t)(jt * 128 + w * 32 + (lane >> 2)) * K + (lane & 3) * 8;
  __hip_bfloat16* lA0 = As + w * 1024;   // 32 rows * 32 k
  __hip_bfloat16* lB0 = Bs + w * 1024;
  size_t gstep16 = (size_t)16 * K;

  f32x4 acc[4][4];
#pragma unroll
  for (int m = 0; m < 4; ++m)
#pragma unroll
    for (int n = 0; n < 4; ++n) acc[m][n] = (f32x4){0.f, 0.f, 0.f, 0.f};

  int fr = lane & 15;            // A-row / B-col within fragment
  int kg = (lane >> 4) * 8;      // k offset: SAME mapping for A and B
  const __hip_bfloat16* raA = As + (size_t)(wr * 64 + fr) * 32 + kg;
  const __hip_bfloat16* raB = Bs + (size_t)(wc * 64 + fr) * 32 + kg;

  for (int k0 = 0; k0 < K; k0 += 32) {
    __syncthreads();  // prior iter's ds_reads done before overwrite
    gload16(ga, lA0);
    gload16(ga + gstep16, lA0 + 512);
    gload16(gb, lB0);
    gload16(gb + gstep16, lB0 + 512);
    ga += 32; gb += 32;
    __syncthreads();  // compiler drains vmcnt before s_barrier -> LDS ready
    bf16x8v a[4], b[4];
#pragma unroll
    for (int m = 0; m < 4; ++m) a[m] = *(const bf16x8v*)(raA + m * 512);
#pragma unroll
    for (int n = 0; n < 4; ++n) b[n] = *(const bf16x8v*)(raB + n * 512);
#pragma unroll
    for (int m = 0; m < 4; ++m)
#pragma unroll
      for (int n = 0; n < 4; ++n)
        acc[m][n] = __builtin_amdgcn_mfma_f32_16x16x32_bf16(a[m], b[n], acc[m][n], 0, 0, 0);
  }

  // C/D layout (HW-verified m89/m91): col = lane&15, row = (lane>>4)*4 + reg
  int row0 = rt * 128 + wr * 64 + (lane >> 4) * 4;
  int col0 = jt * 128 + wc * 64 + fr;
#pragma unroll
  for (int n = 0; n < 4; ++n) {
    int col = col0 + n * 16;
    float bv = bias ? bias[col] : 0.f;
#pragma unroll
    for (int m = 0; m < 4; ++m) {
#pragma unroll
      for (int j = 0; j < 4; ++j) {
        float v = acc[m][n][j] + bv;
        if (relu) v = fmaxf(v, 0.f);
        size_t idx = (size_t)(row0 + m * 16 + j) * J + col;
        if (out_bf16) ((__hip_bfloat16*)Cv)[idx] = __float2bfloat16(v);
        else ((float*)Cv)[idx] = v;
      }
    }
  }
}

// ---------------------------------------------------------------------------
// Generic fp32 GEMM (kept for comb/g1/g2 small GEMMs with fp32 consumers)
// ---------------------------------------------------------------------------
__global__ __launch_bounds__(256) void k_gemm128(const float* __restrict__ A,
                                                 const int* __restrict__ ridx,
                                                 int rstride,
                                                 const float* __restrict__ W,
                                                 const float* __restrict__ bias,
                                                 float* __restrict__ C,
                                                 int R, int K, int J, int relu,
                                                 int out_bf16) {
  __shared__ float As[16][132];
  __shared__ float Ws[16][132];
  int njt = J >> 7;
  int rt = blockIdx.x / njt;
  int jt = blockIdx.x % njt;
  int tid = threadIdx.x;
  int tx = tid & 15, ty = tid >> 4;

  int row2 = tid >> 1;
  int kq = (tid & 1) * 4;
  int gr = rt * 128 + row2;
  const float* arow = A + (size_t)(ridx ? ridx[gr] : gr) * rstride;
  const float* wrow = W + (size_t)(jt * 128 + row2) * K;

  float acc[8][8];
#pragma unroll
  for (int i = 0; i < 8; ++i)
#pragma unroll
    for (int j = 0; j < 8; ++j) acc[i][j] = 0.f;

  for (int k0 = 0; k0 < K; k0 += 16) {
    float4 av0 = *(const float4*)(arow + k0 + kq);
    float4 av1 = *(const float4*)(arow + k0 + kq + 8);
    float4 wv0 = *(const float4*)(wrow + k0 + kq);
    float4 wv1 = *(const float4*)(wrow + k0 + kq + 8);
    __syncthreads();
    As[kq + 0][row2] = av0.x; As[kq + 1][row2] = av0.y;
    As[kq + 2][row2] = av0.z; As[kq + 3][row2] = av0.w;
    As[kq + 8][row2] = av1.x; As[kq + 9][row2] = av1.y;
    As[kq + 10][row2] = av1.z; As[kq + 11][row2] = av1.w;
    Ws[kq + 0][row2] = wv0.x; Ws[kq + 1][row2] = wv0.y;
    Ws[kq + 2][row2] = wv0.z; Ws[kq + 3][row2] = wv0.w;
    Ws[kq + 8][row2] = wv1.x; Ws[kq + 9][row2] = wv1.y;
    Ws[kq + 10][row2] = wv1.z; Ws[kq + 11][row2] = wv1.w;
    __syncthreads();
#pragma unroll
    for (int kk = 0; kk < 16; ++kk) {
      float a[8], b[8];
      *(float4*)&a[0] = *(const float4*)&As[kk][ty * 4];
      *(float4*)&a[4] = *(const float4*)&As[kk][64 + ty * 4];
      *(float4*)&b[0] = *(const float4*)&Ws[kk][tx * 4];
      *(float4*)&b[4] = *(const float4*)&Ws[kk][64 + tx * 4];
#pragma unroll
      for (int i = 0; i < 8; ++i)
#pragma unroll
        for (int j = 0; j < 8; ++j) acc[i][j] += a[i] * b[j];
    }
  }

  int col0 = jt * 128 + tx * 4;
  int col1 = jt * 128 + 64 + tx * 4;
  float b0[4], b1[4];
#pragma unroll
  for (int j = 0; j < 4; ++j) {
    b0[j] = bias ? bias[col0 + j] : 0.f;
    b1[j] = bias ? bias[col1 + j] : 0.f;
  }
#pragma unroll
  for (int i = 0; i < 8; ++i) {
    int row = rt * 128 + ((i < 4) ? (ty * 4 + i) : (64 + ty * 4 + i - 4));
    float v0[4], v1[4];
#pragma unroll
    for (int j = 0; j < 4; ++j) {
      float x0 = acc[i][j] + b0[j];
      float x1 = acc[i][j + 4] + b1[j];
      if (relu) { x0 = fmaxf(x0, 0.f); x1 = fmaxf(x1, 0.f); }
      v0[j] = x0; v1[j] = x1;
    }
    if (out_bf16) {
      __hip_bfloat16* Cb = (__hip_bfloat16*)C;
      union { ushort4 u; __hip_bfloat16 b[4]; } p0, p1;
#pragma unroll
      for (int j = 0; j < 4; ++j) { p0.b[j] = __float2bfloat16(v0[j]); p1.b[j] = __float2bfloat16(v1[j]); }
      *(ushort4*)(Cb + (size_t)row * J + col0) = p0.u;
      *(ushort4*)(Cb + (size_t)row * J + col1) = p1.u;
    } else {
      *(float4*)(C + (size_t)row * J + col0) = *(float4*)v0;
      *(float4*)(C + (size_t)row * J + col1) = *(float4*)v1;
    }
  }
}

// ---------------------------------------------------------------------------
// GRU recurrence v3 (bf16 gi input)
// ---------------------------------------------------------------------------
__global__ __launch_bounds__(512, 2) void k_gru3(const __hip_bfloat16* __restrict__ gi,
                                                 const float* __restrict__ whh,
                                                 const float* __restrict__ bhh,
                                                 float* __restrict__ out,
                                                 int L) {
  __shared__ float hs[4][132];
  __shared__ float parts[4][8][388];
  int tid = threadIdx.x;
  int d = blockIdx.y;
  int n0 = blockIdx.x * 4;
  int ks = tid >> 6;
  int rg = tid & 63;
  int kb = ks * 16;
  const float* wbase = whh + (size_t)d * 384 * 128;

  float4 w4[6][4];
#pragma unroll
  for (int r = 0; r < 6; ++r) {
    const float* wr = wbase + (size_t)(r * 64 + rg) * 128 + kb;
#pragma unroll
    for (int q = 0; q < 4; ++q) w4[r][q] = ((const float4*)wr)[q];
  }

  int sg = tid >> 7, jg = tid & 127;
  const float* bh = bhh + d * 384;
  float br = bh[jg], bz = bh[128 + jg], bn = bh[256 + jg];

  for (int i = tid; i < 4 * 132; i += 512) ((float*)hs)[i] = 0.f;
  __syncthreads();

  int t = d ? (L - 1) : 0;
  int dt = d ? -1 : 1;

  for (int step = 0; step < L; ++step, t += dt) {
    const __hip_bfloat16* g = gi + (size_t)((n0 + sg) * L + t) * 768 + d * 384;
    float pgr = b2f(g[jg]), pgz = b2f(g[128 + jg]), pgn = b2f(g[256 + jg]);

    float acc[4][6];
#pragma unroll
    for (int s = 0; s < 4; ++s)
#pragma unroll
      for (int r = 0; r < 6; ++r) acc[s][r] = 0.f;
#pragma unroll
    for (int s = 0; s < 4; ++s) {
#pragma unroll
      for (int q = 0; q < 4; ++q) {
        float4 hv = *(const float4*)&hs[s][kb + q * 4];
#pragma unroll
        for (int r = 0; r < 6; ++r) {
          acc[s][r] += w4[r][q].x * hv.x + w4[r][q].y * hv.y +
                       w4[r][q].z * hv.z + w4[r][q].w * hv.w;
        }
      }
    }
#pragma unroll
    for (int s = 0; s < 4; ++s)
#pragma unroll
      for (int r = 0; r < 6; ++r) parts[s][ks][r * 64 + rg] = acc[s][r];
    __syncthreads();
    {
      float sr = 0.f, sz = 0.f, sn = 0.f;
#pragma unroll
      for (int k = 0; k < 8; ++k) {
        sr += parts[sg][k][jg];
        sz += parts[sg][k][128 + jg];
        sn += parts[sg][k][256 + jg];
      }
      float r = sigf(pgr + sr + br);
      float z = sigf(pgz + sz + bz);
      float nn = tanhf(pgn + r * (sn + bn));
      float hold = hs[sg][jg];
      float hnew = (1.f - z) * nn + z * hold;
      hs[sg][jg] = hnew;
      out[(size_t)((n0 + sg) * L + t) * 256 + d * 128 + jg] = hnew;
    }
    __syncthreads();
  }
}

// ---------------------------------------------------------------------------
// Attention pool (one block per n)
// ---------------------------------------------------------------------------
__global__ __launch_bounds__(256) void k_attn_pool(const float* __restrict__ score_src,
                                                   int s_ns, int s_ls,
                                                   const float* __restrict__ val_src,
                                                   int v_ns, int v_ls,
                                                   const float* __restrict__ w,
                                                   const float* __restrict__ bptr,
                                                   float* __restrict__ dst,
                                                   int dst_stride, int L) {
  __shared__ float wts[64];
  int n = blockIdx.x;
  int tid = threadIdx.x;
  if (tid < 64) {
    float a = -INFINITY;
    if (tid < L) {
      const float* row = score_src + (size_t)n * s_ns + (size_t)tid * s_ls;
      float s = bptr[0];
      for (int h = 0; h < 256; h += 4) {
        float4 v = *(const float4*)(row + h);
        float4 wv = *(const float4*)(w + h);
        s += v.x * wv.x + v.y * wv.y + v.z * wv.z + v.w * wv.w;
      }
      a = s;
    }
    float mx = a;
#pragma unroll
    for (int off = 32; off; off >>= 1) mx = fmaxf(mx, __shfl_xor(mx, off));
    float e = (tid < L) ? expf(a - mx) : 0.f;
    float ss = e;
#pragma unroll
    for (int off = 32; off; off >>= 1) ss += __shfl_xor(ss, off);
    if (tid < L) wts[tid] = e / ss;
  }
  __syncthreads();
  float acc = 0.f;
  for (int l = 0; l < L; ++l)
    acc += wts[l] * val_src[(size_t)n * v_ns + (size_t)l * v_ls + tid];
  dst[(size_t)n * dst_stride + tid] = acc;
}

// ---------------------------------------------------------------------------
// xn[n][m][h] = 0.5*label_tab[lbl][h] + (1/16)*sum_t tok_tab[id][h]  (bf16 out)
// ---------------------------------------------------------------------------
__global__ __launch_bounds__(256) void k_xn_bf16(const float* __restrict__ label_tab,
                                                 const float* __restrict__ tok_tab,
                                                 const int* __restrict__ lbl_ids,
                                                 const int* __restrict__ tok_ids,
                                                 __hip_bfloat16* __restrict__ xnb) {
  int nm = blockIdx.x;
  int h = threadIdx.x;
  const int* tids = tok_ids + (size_t)nm * 8;
  float s = 0.f;
#pragma unroll
  for (int t = 0; t < 8; ++t) s += tok_tab[(size_t)tids[t] * 256 + h];
  float v = 0.5f * label_tab[(size_t)lbl_ids[nm] * 256 + h] + 0.0625f * s;
  xnb[(size_t)nm * 256 + h] = __float2bfloat16(v);
}

// ---------------------------------------------------------------------------
// TreeLSTM combine (step m): gates from bf16 XWALL + gathered bf16 HU.
// Dual-writes h as bf16 (HBF) for the MFMA projection.
// ---------------------------------------------------------------------------
__global__ __launch_bounds__(256) void k_tl_combine4(const __hip_bfloat16* __restrict__ HU,
                                                     const __hip_bfloat16* __restrict__ XWALL,
                                                     const int* __restrict__ ch,
                                                     const int* __restrict__ msk,
                                                     float* __restrict__ h_arr,
                                                     float* __restrict__ c_arr,
                                                     __hip_bfloat16* __restrict__ hbf,
                                                     int m) {
  int n = blockIdx.x, h = threadIdx.x;
  const __hip_bfloat16* xw = XWALL + ((size_t)(n * 64 + m)) * 1024;
  float si = b2f(xw[h]), so = b2f(xw[256 + h]), su = b2f(xw[512 + h]);
  float xfv = b2f(xw[768 + h]);
  const int* chp = ch + ((size_t)(n * 64 + m)) * 4;
  const int* mkp = msk + ((size_t)(n * 64 + m)) * 4;
  float cs = 0.f;
#pragma unroll
  for (int c = 0; c < 4; ++c) {
    if (mkp[c]) {
      int cc = chp[c];
      const __hip_bfloat16* hu = HU + ((size_t)cc * 512 + n) * 1024;
      si += b2f(hu[h]);
      so += b2f(hu[256 + h]);
      su += b2f(hu[512 + h]);
      float fg = sigf(xfv + b2f(hu[768 + h]));
      cs += fg * c_arr[((size_t)cc * 512 + n) * 256 + h];
    }
  }
  float iv = sigf(si), ov = sigf(so), uv = tanhf(su);
  float cn = iv * uv + cs;
  float hn = ov * tanhf(cn);
  h_arr[((size_t)m * 512 + n) * 256 + h] = hn;
  c_arr[((size_t)m * 512 + n) * 256 + h] = cn;
  hbf[(size_t)n * 256 + h] = __float2bfloat16(hn);
}

// ---------------------------------------------------------------------------
// Graph kernels
// ---------------------------------------------------------------------------
__global__ __launch_bounds__(256) void k_edge_deg(const int* __restrict__ edges,
                                                  int* __restrict__ deg, int E) {
  int i = blockIdx.x * 256 + threadIdx.x;
  if (i < E) {
    atomicAdd(&deg[edges[2 * i]], 1);
    atomicAdd(&deg[edges[2 * i + 1]], 1);
  }
}

__global__ __launch_bounds__(256) void k_nei(const int* __restrict__ edges,
                                             const float* __restrict__ x,
                                             float* __restrict__ nei_sum) {
  int e = blockIdx.x, h = threadIdx.x;
  int a = edges[2 * e], b = edges[2 * e + 1];
  atomicAdd(&nei_sum[(size_t)a * 256 + h], x[(size_t)b * 256 + h]);
  atomicAdd(&nei_sum[(size_t)b * 256 + h], x[(size_t)a * 256 + h]);
}

__global__ __launch_bounds__(256) void k_xcat(const float* __restrict__ x,
                                              const float* __restrict__ nei_sum,
                                              const int* __restrict__ deg,
                                              float* __restrict__ xcat) {
  int n = blockIdx.x, h = threadIdx.x;
  xcat[(size_t)n * 512 + h] = x[(size_t)n * 256 + h];
  float d = fmaxf((float)deg[n], 1.f);
  xcat[(size_t)n * 512 + 256 + h] = nei_sum[(size_t)n * 256 + h] / d;
}

__global__ __launch_bounds__(256) void k_spmm_self(const float* __restrict__ y,
                                                   const int* __restrict__ deg,
                                                   float* __restrict__ ob) {
  int n = blockIdx.x, h = threadIdx.x;
  float dis2 = 1.f / (float)(deg[n] + 1);
  ob[(size_t)n * 256 + h] = dis2 * y[(size_t)n * 256 + h];
}

__global__ __launch_bounds__(256) void k_spmm_edge(const float* __restrict__ y,
                                                   const int* __restrict__ deg,
                                                   const int* __restrict__ edges,
                                                   float* __restrict__ ob) {
  int e = blockIdx.x, h = threadIdx.x;
  int a = edges[2 * e], b = edges[2 * e + 1];
  float w = (1.f / sqrtf((float)(deg[a] + 1))) * (1.f / sqrtf((float)(deg[b] + 1)));
  atomicAdd(&ob[(size_t)a * 256 + h], w * y[(size_t)b * 256 + h]);
  atomicAdd(&ob[(size_t)b * 256 + h], w * y[(size_t)a * 256 + h]);
}

__global__ __launch_bounds__(256) void k_relu_inplace(float* __restrict__ p) {
  int i = blockIdx.x * 256 + threadIdx.x;
  p[i] = fmaxf(p[i], 0.f);
}

__global__ __launch_bounds__(256) void k_final(const float* __restrict__ h2,
                                               const float* __restrict__ w1,
                                               const float* __restrict__ b1,
                                               const float* __restrict__ w2,
                                               const float* __restrict__ b2,
                                               float* __restrict__ outp) {
  __shared__ float gv[512];
  __shared__ float zz[256];
  int tid = threadIdx.x;
  float mn = 0.f, mx = -INFINITY;
  for (int n = 0; n < 512; ++n) {
    float v = h2[(size_t)n * 256 + tid];
    mn += v;
    mx = fmaxf(mx, v);
  }
  gv[tid] = mn / 512.f;
  gv[256 + tid] = mx;
  __syncthreads();
  float acc = b1[tid];
  for (int k = 0; k < 512; ++k) acc += gv[k] * w1[(size_t)tid * 512 + k];
  zz[tid] = fmaxf(acc, 0.f) * w2[tid];
  __syncthreads();
  for (int s = 128; s; s >>= 1) {
    if (tid < s) zz[tid] += zz[tid + s];
    __syncthreads();
  }
  if (tid == 0) outp[0] = zz[0] + b2[0];
}

// ---------------------------------------------------------------------------
// Host launch
// ---------------------------------------------------------------------------
extern "C" void kernel_launch(void* const* d_in, const int* in_sizes, int n_in,
                              void* d_out, int out_size, void* d_ws, size_t ws_size,
                              hipStream_t stream) {
  const int* seq_tokens    = (const int*)d_in[0];
  const int* ast_children  = (const int*)d_in[1];
  const void* ast_mask_raw = (const void*)d_in[2];
  const int* ast_label_ids = (const int*)d_in[3];
  const int* ast_tok_ids   = (const int*)d_in[4];
  const int* ctx_nei       = (const int*)d_in[5];
  const int* edges         = (const int*)d_in[6];
  const float* seq_emb  = (const float*)d_in[7];
  const float* seq_wih  = (const float*)d_in[8];
  const float* seq_whh  = (const float*)d_in[9];
  const float* seq_bih  = (const float*)d_in[10];
  const float* seq_bhh  = (const float*)d_in[11];
  const float* seq_pw   = (const float*)d_in[12];
  const float* seq_pb   = (const float*)d_in[13];
  const float* ctx_wih  = (const float*)d_in[14];
  const float* ctx_whh  = (const float*)d_in[15];
  const float* ctx_bih  = (const float*)d_in[16];
  const float* ctx_bhh  = (const float*)d_in[17];
  const float* ctx_pw   = (const float*)d_in[18];
  const float* ctx_pb   = (const float*)d_in[19];
  const float* ast_label_tab = (const float*)d_in[20];
  const float* ast_tok_tab   = (const float*)d_in[21];
  const float* ast_pw   = (const float*)d_in[22];
  const float* ast_pb   = (const float*)d_in[23];
  const float* tl_wiou  = (const float*)d_in[24];
  const float* tl_biou  = (const float*)d_in[25];
  const float* tl_uiou  = (const float*)d_in[26];
  const float* tl_wf    = (const float*)d_in[27];
  const float* tl_bf    = (const float*)d_in[28];
  const float* tl_uf    = (const float*)d_in[29];
  const float* fa_wih   = (const float*)d_in[30];
  const float* fa_whh   = (const float*)d_in[31];
  const float* fa_bih   = (const float*)d_in[32];
  const float* fa_bhh   = (const float*)d_in[33];
  const float* fa_aw    = (const float*)d_in[34];
  const float* fa_ab    = (const float*)d_in[35];
  const float* comb_w   = (const float*)d_in[36];
  const float* comb_b   = (const float*)d_in[37];
  const float* g1_w     = (const float*)d_in[38];
  const float* g1_b     = (const float*)d_in[39];
  const float* g2_w     = (const float*)d_in[40];
  const float* g2_b     = (const float*)d_in[41];
  const float* cls_w1   = (const float*)d_in[42];
  const float* cls_b1   = (const float*)d_in[43];
  const float* cls_w2   = (const float*)d_in[44];
  const float* cls_b2   = (const float*)d_in[45];
  float* outp = (float*)d_out;
  float* ws = (float*)d_ws;
  int E = in_sizes[6] / 2;

  // ----- workspace layout (floats) -----
  size_t off = 0;
  auto take = [&](size_t n) { size_t o = off; off += n; return o; };
  const size_t F_FEATS = take(512 * 5 * 256);
  const size_t F_X     = take(512 * 256);
  const size_t F_X2    = take(512 * 256);
  const size_t F_Y     = take(512 * 256);
  const size_t F_H1    = take(512 * 256);
  const size_t F_H2    = take(512 * 256);
  const size_t F_XCAT  = take(512 * 512);
  const size_t F_NEI   = take(512 * 256);
  const size_t F_DEG   = take(512);
  const size_t F_FLAG  = take(16);
  const size_t F_MSK   = take(512 * 64 * 4);
  const size_t F_WXW   = take(1024 * 256);
  const size_t F_WXB   = take(1024);
  const size_t F_WPROJ = take(1024 * 256);
  const size_t F_REGION = take(83886080);  // shared phase region
  (void)ws_size;

  float* FEATS = ws + F_FEATS;
  float* X     = ws + F_X;
  float* X2    = ws + F_X2;
  float* Y     = ws + F_Y;
  float* H1    = ws + F_H1;
  float* H2    = ws + F_H2;
  float* XCAT  = ws + F_XCAT;
  float* NEI   = ws + F_NEI;
  int*   DEG   = (int*)(ws + F_DEG);
  int*   FLAG  = (int*)(ws + F_FLAG);
  int*   MSK   = (int*)(ws + F_MSK);
  float* WXW   = ws + F_WXW;
  float* WXB   = ws + F_WXB;
  float* WPROJ = ws + F_WPROJ;
  float* REG   = ws + F_REGION;
  // enc/ctx phase
  __hip_bfloat16* GI16  = (__hip_bfloat16*)REG;             // 32768x768 bf16
  float* OUT   = REG + 13631488;                            // 8.39M fp32
  // TL phase
  __hip_bfloat16* XWALL16 = (__hip_bfloat16*)REG;           // 32768x1024 bf16
  float* HARR  = REG + 17000000;                            // 8.39M
  float* CARR  = REG + 25500000;                            // 8.39M
  __hip_bfloat16* HU16 = (__hip_bfloat16*)(REG + 34000000); // 64x512x1024 bf16
  // fa phase
  __hip_bfloat16* GIFA16 = (__hip_bfloat16*)REG;            // 2560x768 bf16
  float* OUTFA = REG + 1966080;
  // bf16 MFMA scratch (above all per-phase regions; [60M, 83.9M) is free in
  // every phase)
  __hip_bfloat16* ABF     = (__hip_bfloat16*)(REG + 60000000); // 32768x256 bf16
  __hip_bfloat16* WSEQBF  = (__hip_bfloat16*)(REG + 65000000); // 2304x256
  __hip_bfloat16* WCTXBF  = (__hip_bfloat16*)(REG + 65400000); // 768x256
  __hip_bfloat16* WFABF   = (__hip_bfloat16*)(REG + 65600000); // 768x256
  __hip_bfloat16* WXWBF   = (__hip_bfloat16*)(REG + 65800000); // 1024x256
  __hip_bfloat16* WPROJBF = (__hip_bfloat16*)(REG + 66100000); // 1024x256
  __hip_bfloat16* HBF     = (__hip_bfloat16*)(REG + 66500000); // 512x256

  auto gemm = [&](const float* A, const int* ridx, int rstride, const float* W,
                  const float* bias, float* C, int R, int K, int J, int relu,
                  int obf) {
    dim3 g((R / 128) * (J / 128));
    k_gemm128<<<g, 256, 0, stream>>>(A, ridx, rstride, W, bias, C, R, K, J, relu, obf);
  };
  auto cvt = [&](const float* A, const int* ridx, int rstride,
                 __hip_bfloat16* ob, int R) {
    k_cvt_bf16<<<R / 8, 256, 0, stream>>>(A, ridx, rstride, ob);
  };
  auto mgemm = [&](const __hip_bfloat16* A, const __hip_bfloat16* W,
                   const float* bias, void* C, int R, int K, int J, int relu,
                   int obf) {
    dim3 g((R / 128) * (J / 128));
    k_gemm_mfma<<<g, 256, 0, stream>>>(A, W, bias, C, R, K, J, relu, obf);
  };

  // ---- prep ----
  k_build_wx<<<1024, 256, 0, stream>>>(tl_wiou, tl_wf, tl_biou, tl_bf, WXW, WXB);
  k_build_wproj<<<1024, 256, 0, stream>>>(tl_uiou, tl_uf, WPROJ);
  k_zero_misc<<<512, 256, 0, stream>>>(NEI, DEG, FLAG);
  k_mask_detect<<<128, 256, 0, stream>>>((const unsigned*)ast_mask_raw, FLAG);
  k_mask_convert<<<512, 256, 0, stream>>>(ast_mask_raw, FLAG, MSK);
  // weight panels -> bf16 (once per launch)
  cvt(seq_wih, nullptr, 256, WSEQBF, 2304);
  cvt(ctx_wih, nullptr, 256, WCTXBF, 768);
  cvt(fa_wih, nullptr, 256, WFABF, 768);
  cvt(WXW, nullptr, 256, WXWBF, 1024);
  cvt(WPROJ, nullptr, 256, WPROJBF, 1024);

  // ---- 3 sequence encoders: slots 0 (stmt), 2 (varn), 3 (vart) ----
  const int slot_of[3] = {0, 2, 3};
  for (int e = 0; e < 3; ++e) {
    cvt(seq_emb + (size_t)e * 50000 * 256, seq_tokens + (size_t)e * 32768, 256,
        ABF, 32768);
    mgemm(ABF, WSEQBF + (size_t)e * 768 * 256, seq_bih + (size_t)e * 768,
          GI16, 32768, 256, 768, 0, 1);
    k_gru3<<<dim3(128, 2), 512, 0, stream>>>(GI16, seq_whh + (size_t)e * 2 * 384 * 128,
                                             seq_bhh + (size_t)e * 768, OUT, 64);
    k_attn_pool<<<512, 256, 0, stream>>>(OUT, 64 * 256, 256, OUT, 64 * 256, 256,
                                         seq_pw + e * 256, seq_pb + e,
                                         FEATS + slot_of[e] * 256, 1280, 64);
  }

  // ---- ctx encoder (needs stmt slot0): slot 4 ----
  cvt(FEATS, ctx_nei, 1280, ABF, 4096);
  mgemm(ABF, WCTXBF, ctx_bih, GI16, 4096, 256, 768, 0, 1);
  k_gru3<<<dim3(128, 2), 512, 0, stream>>>(GI16, ctx_whh, ctx_bhh, OUT, 8);
  k_attn_pool<<<512, 256, 0, stream>>>(OUT, 8 * 256, 256, OUT, 8 * 256, 256,
                                       ctx_pw, ctx_pb, FEATS + 4 * 256, 1280, 8);

  // ---- AST TreeLSTM: slot 1 ----
  k_xn_bf16<<<32768, 256, 0, stream>>>(ast_label_tab, ast_tok_tab, ast_label_ids,
                                       ast_tok_ids, ABF);
  mgemm(ABF, WXWBF, WXB, XWALL16, 32768, 256, 1024, 0, 1);
  for (int m = 0; m < 64; ++m) {
    k_tl_combine4<<<512, 256, 0, stream>>>(HU16, XWALL16, ast_children, MSK,
                                           HARR, CARR, HBF, m);
    if (m < 63)
      mgemm(HBF, WPROJBF, nullptr, HU16 + (size_t)m * 512 * 1024,
            512, 256, 1024, 0, 1);
  }
  k_attn_pool<<<512, 256, 0, stream>>>(HARR, 256, 512 * 256, HARR, 256, 512 * 256,
                                       ast_pw, ast_pb, FEATS + 1 * 256, 1280, 64);

  // ---- feature-attention biGRU over the 5 slots -> x ----
  cvt(FEATS, nullptr, 256, ABF, 2560);
  mgemm(ABF, WFABF, fa_bih, GIFA16, 2560, 256, 768, 0, 1);
  k_gru3<<<dim3(128, 2), 512, 0, stream>>>(GIFA16, fa_whh, fa_bhh, OUTFA, 5);
  k_attn_pool<<<512, 256, 0, stream>>>(OUTFA, 5 * 256, 256, FEATS, 1280, 256,
                                       fa_aw, fa_ab, X, 256, 5);

  // ---- graph section ----
  k_edge_deg<<<(E + 255) / 256, 256, 0, stream>>>(edges, DEG, E);
  k_nei<<<E, 256, 0, stream>>>(edges, X, NEI);
  k_xcat<<<512, 256, 0, stream>>>(X, NEI, DEG, XCAT);
  gemm(XCAT, nullptr, 512, comb_w, comb_b, X2, 512, 512, 256, 1, 0);
  gemm(X2, nullptr, 256, g1_w, g1_b, Y, 512, 256, 256, 0, 0);
  k_spmm_self<<<512, 256, 0, stream>>>(Y, DEG, H1);
  k_spmm_edge<<<E, 256, 0, stream>>>(Y, DEG, edges, H1);
  k_relu_inplace<<<512, 256, 0, stream>>>(H1);
  gemm(H1, nullptr, 256, g2_w, g2_b, Y, 512, 256, 256, 0, 0);
  k_spmm_self<<<512, 256, 0, stream>>>(Y, DEG, H2);
  k_spmm_edge<<<E, 256, 0, stream>>>(Y, DEG, edges, H2);
  k_relu_inplace<<<512, 256, 0, stream>>>(H2);
  k_final<<<1, 256, 0, stream>>>(H2, cls_w1, cls_b1, cls_w2, cls_b2, outp);
}

// Round 3
// 2100.751 us; speedup vs baseline: 1.3750x; 1.0470x over previous
//
#include <hip/hip_runtime.h>
#include <hip/hip_bf16.h>
#include <cmath>

// ---------------------------------------------------------------------------
// Model dims: H=256 HID=128 V=50000 LV=200 N=512 L=64 M=64 C=4 T=8 K=8
// NOTE (round 5 lesson): cooperative grid.sync() costs ~37us on MI355X —
// never use it for a 126-sync loop; per-step kernel launches (~2-3us) win.
// NOTE (round 6): big GEMMs on bf16 MFMA (m97-style 128x128 tile).
// NOTE (round 7): GRU recurrence on MFMA: per block 16 seqs, Whh held in
// VGPRs as bf16 fragments (loaded once), H in LDS bf16 (pad 136 -> 2-way
// bank aliasing, free per m136), gates fp32 on thread-owned h registers,
// gi prefetched into regs before MFMA so L2/L3 latency hides under matmul.
// A/B frags share the lane-group->k mapping (permutation cancels); C/D is
// the HW-verified col=lane&15, row=(lane>>4)*4+reg.
// NOTE (round 8): round-7 bench died to container infra failure (no GPU
// verdict); kernel re-audited (barriers uniform, bounds checked, LDS 29KB,
// workspace offsets verified) and resubmitted unchanged.
// ---------------------------------------------------------------------------

__device__ __forceinline__ float sigf(float x) { return 1.f / (1.f + expf(-x)); }
__device__ __forceinline__ float b2f(__hip_bfloat16 x) { return __bfloat162float(x); }
__device__ __forceinline__ float bu2f(unsigned short u) {
  union { float f; unsigned i; } v; v.i = ((unsigned)u) << 16; return v.f;
}

typedef __attribute__((ext_vector_type(8))) short bf16x8v;  // 8 bf16 (4 VGPRs)
typedef __attribute__((ext_vector_type(4))) float f32x4;

__device__ __forceinline__ void gload16(const __hip_bfloat16* g, __hip_bfloat16* l) {
  __builtin_amdgcn_global_load_lds((const __attribute__((address_space(1))) void*)g,
                                   (__attribute__((address_space(3))) void*)l, 16, 0, 0);
}

// ---------------------------------------------------------------------------
// WXALL weights: [wiou (768) | wf (256)] rows x 256, bias [biou | bf]
// ---------------------------------------------------------------------------
__global__ __launch_bounds__(256) void k_build_wx(const float* __restrict__ wiou,
                                                  const float* __restrict__ wf,
                                                  const float* __restrict__ biou,
                                                  const float* __restrict__ bf,
                                                  float* __restrict__ w,
                                                  float* __restrict__ b) {
  int i = blockIdx.x * 256 + threadIdx.x;
  if (i < 1024 * 256) {
    int j = i >> 8, k = i & 255;
    w[i] = (j < 768) ? wiou[j * 256 + k] : wf[(j - 768) * 256 + k];
  }
  if (i < 1024) b[i] = (i < 768) ? biou[i] : bf[i - 768];
}

// WPROJ: [uiou (768) | uf (256)] rows x 256
__global__ __launch_bounds__(256) void k_build_wproj(const float* __restrict__ uiou,
                                                     const float* __restrict__ uf,
                                                     float* __restrict__ w) {
  int i = blockIdx.x * 256 + threadIdx.x;
  if (i >= 1024 * 256) return;
  int j = i >> 8, k = i & 255;
  w[i] = (j < 768) ? uiou[j * 256 + k] : uf[(j - 768) * 256 + k];
}

__global__ __launch_bounds__(256) void k_zero_misc(float* __restrict__ nei_sum,
                                                   int* __restrict__ deg,
                                                   int* __restrict__ flag) {
  int i = blockIdx.x * 256 + threadIdx.x;
  if (i < 512 * 256) nei_sum[i] = 0.f;
  if (i < 512) deg[i] = 0;
  if (i == 0) *flag = 0;
}

// bool-mask dtype detector (int32 vs byte-packed)
__global__ __launch_bounds__(256) void k_mask_detect(const unsigned* __restrict__ raw,
                                                     int* __restrict__ flag) {
  int i = blockIdx.x * 256 + threadIdx.x;
  if (i < 32768) {
    if (raw[i] > 1u) atomicOr(flag, 1);
  }
}

__global__ __launch_bounds__(256) void k_mask_convert(const void* __restrict__ raw,
                                                      const int* __restrict__ flag,
                                                      int* __restrict__ msk) {
  int i = blockIdx.x * 256 + threadIdx.x;
  if (i >= 512 * 64 * 4) return;
  int v;
  if (*flag) v = ((const unsigned char*)raw)[i] != 0;
  else       v = ((const int*)raw)[i] != 0;
  msk[i] = v;
}

// ---------------------------------------------------------------------------
// fp32 -> bf16 row gather/convert: out[r][0:256] = bf16(A[(ridx?ridx[r]:r)*rstride + 0:256])
// one block = 8 rows; K fixed at 256.
// ---------------------------------------------------------------------------
__global__ __launch_bounds__(256) void k_cvt_bf16(const float* __restrict__ A,
                                                  const int* __restrict__ ridx,
                                                  int rstride,
                                                  __hip_bfloat16* __restrict__ out) {
  int r = blockIdx.x * 8 + (threadIdx.x >> 5);
  int k = (threadIdx.x & 31) * 8;
  const float* src = A + (size_t)(ridx ? ridx[r] : r) * rstride + k;
  float4 v0 = *(const float4*)src;
  float4 v1 = *(const float4*)(src + 4);
  union { ushort4 u; __hip_bfloat16 b[4]; } p0, p1;
  p0.b[0] = __float2bfloat16(v0.x); p0.b[1] = __float2bfloat16(v0.y);
  p0.b[2] = __float2bfloat16(v0.z); p0.b[3] = __float2bfloat16(v0.w);
  p1.b[0] = __float2bfloat16(v1.x); p1.b[1] = __float2bfloat16(v1.y);
  p1.b[2] = __float2bfloat16(v1.z); p1.b[3] = __float2bfloat16(v1.w);
  __hip_bfloat16* dst = out + (size_t)r * 256 + k;
  *(ushort4*)dst = p0.u;
  *(ushort4*)(dst + 4) = p1.u;
}

// ---------------------------------------------------------------------------
// bf16 MFMA GEMM: C[R x J] = A[R x K] @ W[J x K]^T (+bias, relu opt).
// 128x128 tile, BK=32, 256 threads = 4 waves in 2x2, each wave 64x64 out
// (4x4 fragments of 16x16x32). global_load_lds width-16 staging, linear LDS.
// Requires R%128==0, J%128==0, K%32==0.
// ---------------------------------------------------------------------------
__global__ __launch_bounds__(256) void k_gemm_mfma(const __hip_bfloat16* __restrict__ A,
                                                   const __hip_bfloat16* __restrict__ W,
                                                   const float* __restrict__ bias,
                                                   void* __restrict__ Cv,
                                                   int R, int K, int J,
                                                   int relu, int out_bf16) {
  __shared__ __align__(16) __hip_bfloat16 As[128 * 32];
  __shared__ __align__(16) __hip_bfloat16 Bs[128 * 32];
  int njt = J >> 7;
  int rt = blockIdx.x / njt;
  int jt = blockIdx.x - rt * njt;
  int tid = threadIdx.x;
  int w = tid >> 6, lane = tid & 63;
  int wr = w >> 1, wc = w & 1;

  const __hip_bfloat16* ga = A + (size_t)(rt * 128 + w * 32 + (lane >> 2)) * K + (lane & 3) * 8;
  const __hip_bfloat16* gb = W + (size_t)(jt * 128 + w * 32 + (lane >> 2)) * K + (lane & 3) * 8;
  __hip_bfloat16* lA0 = As + w * 1024;   // 32 rows * 32 k
  __hip_bfloat16* lB0 = Bs + w * 1024;
  size_t gstep16 = (size_t)16 * K;

  f32x4 acc[4][4];
#pragma unroll
  for (int m = 0; m < 4; ++m)
#pragma unroll
    for (int n = 0; n < 4; ++n) acc[m][n] = (f32x4){0.f, 0.f, 0.f, 0.f};

  int fr = lane & 15;            // A-row / B-col within fragment
  int kg = (lane >> 4) * 8;      // k offset: SAME mapping for A and B
  const __hip_bfloat16* raA = As + (size_t)(wr * 64 + fr) * 32 + kg;
  const __hip_bfloat16* raB = Bs + (size_t)(wc * 64 + fr) * 32 + kg;

  for (int k0 = 0; k0 < K; k0 += 32) {
    __syncthreads();  // prior iter's ds_reads done before overwrite
    gload16(ga, lA0);
    gload16(ga + gstep16, lA0 + 512);
    gload16(gb, lB0);
    gload16(gb + gstep16, lB0 + 512);
    ga += 32; gb += 32;
    __syncthreads();  // compiler drains vmcnt before s_barrier -> LDS ready
    bf16x8v a[4], b[4];
#pragma unroll
    for (int m = 0; m < 4; ++m) a[m] = *(const bf16x8v*)(raA + m * 512);
#pragma unroll
    for (int n = 0; n < 4; ++n) b[n] = *(const bf16x8v*)(raB + n * 512);
#pragma unroll
    for (int m = 0; m < 4; ++m)
#pragma unroll
      for (int n = 0; n < 4; ++n)
        acc[m][n] = __builtin_amdgcn_mfma_f32_16x16x32_bf16(a[m], b[n], acc[m][n], 0, 0, 0);
  }

  // C/D layout (HW-verified m89/m91): col = lane&15, row = (lane>>4)*4 + reg
  int row0 = rt * 128 + wr * 64 + (lane >> 4) * 4;
  int col0 = jt * 128 + wc * 64 + fr;
#pragma unroll
  for (int n = 0; n < 4; ++n) {
    int col = col0 + n * 16;
    float bv = bias ? bias[col] : 0.f;
#pragma unroll
    for (int m = 0; m < 4; ++m) {
#pragma unroll
      for (int j = 0; j < 4; ++j) {
        float v = acc[m][n][j] + bv;
        if (relu) v = fmaxf(v, 0.f);
        size_t idx = (size_t)(row0 + m * 16 + j) * J + col;
        if (out_bf16) ((__hip_bfloat16*)Cv)[idx] = __float2bfloat16(v);
        else ((float*)Cv)[idx] = v;
      }
    }
  }
}

// ---------------------------------------------------------------------------
// Generic fp32 GEMM (kept for comb/g1/g2 small GEMMs with fp32 consumers)
// ---------------------------------------------------------------------------
__global__ __launch_bounds__(256) void k_gemm128(const float* __restrict__ A,
                                                 const int* __restrict__ ridx,
                                                 int rstride,
                                                 const float* __restrict__ W,
                                                 const float* __restrict__ bias,
                                                 float* __restrict__ C,
                                                 int R, int K, int J, int relu,
                                                 int out_bf16) {
  __shared__ float As[16][132];
  __shared__ float Ws[16][132];
  int njt = J >> 7;
  int rt = blockIdx.x / njt;
  int jt = blockIdx.x % njt;
  int tid = threadIdx.x;
  int tx = tid & 15, ty = tid >> 4;

  int row2 = tid >> 1;
  int kq = (tid & 1) * 4;
  int gr = rt * 128 + row2;
  const float* arow = A + (size_t)(ridx ? ridx[gr] : gr) * rstride;
  const float* wrow = W + (size_t)(jt * 128 + row2) * K;

  float acc[8][8];
#pragma unroll
  for (int i = 0; i < 8; ++i)
#pragma unroll
    for (int j = 0; j < 8; ++j) acc[i][j] = 0.f;

  for (int k0 = 0; k0 < K; k0 += 16) {
    float4 av0 = *(const float4*)(arow + k0 + kq);
    float4 av1 = *(const float4*)(arow + k0 + kq + 8);
    float4 wv0 = *(const float4*)(wrow + k0 + kq);
    float4 wv1 = *(const float4*)(wrow + k0 + kq + 8);
    __syncthreads();
    As[kq + 0][row2] = av0.x; As[kq + 1][row2] = av0.y;
    As[kq + 2][row2] = av0.z; As[kq + 3][row2] = av0.w;
    As[kq + 8][row2] = av1.x; As[kq + 9][row2] = av1.y;
    As[kq + 10][row2] = av1.z; As[kq + 11][row2] = av1.w;
    Ws[kq + 0][row2] = wv0.x; Ws[kq + 1][row2] = wv0.y;
    Ws[kq + 2][row2] = wv0.z; Ws[kq + 3][row2] = wv0.w;
    Ws[kq + 8][row2] = wv1.x; Ws[kq + 9][row2] = wv1.y;
    Ws[kq + 10][row2] = wv1.z; Ws[kq + 11][row2] = wv1.w;
    __syncthreads();
#pragma unroll
    for (int kk = 0; kk < 16; ++kk) {
      float a[8], b[8];
      *(float4*)&a[0] = *(const float4*)&As[kk][ty * 4];
      *(float4*)&a[4] = *(const float4*)&As[kk][64 + ty * 4];
      *(float4*)&b[0] = *(const float4*)&Ws[kk][tx * 4];
      *(float4*)&b[4] = *(const float4*)&Ws[kk][64 + tx * 4];
#pragma unroll
      for (int i = 0; i < 8; ++i)
#pragma unroll
        for (int j = 0; j < 8; ++j) acc[i][j] += a[i] * b[j];
    }
  }

  int col0 = jt * 128 + tx * 4;
  int col1 = jt * 128 + 64 + tx * 4;
  float b0[4], b1[4];
#pragma unroll
  for (int j = 0; j < 4; ++j) {
    b0[j] = bias ? bias[col0 + j] : 0.f;
    b1[j] = bias ? bias[col1 + j] : 0.f;
  }
#pragma unroll
  for (int i = 0; i < 8; ++i) {
    int row = rt * 128 + ((i < 4) ? (ty * 4 + i) : (64 + ty * 4 + i - 4));
    float v0[4], v1[4];
#pragma unroll
    for (int j = 0; j < 4; ++j) {
      float x0 = acc[i][j] + b0[j];
      float x1 = acc[i][j + 4] + b1[j];
      if (relu) { x0 = fmaxf(x0, 0.f); x1 = fmaxf(x1, 0.f); }
      v0[j] = x0; v1[j] = x1;
    }
    if (out_bf16) {
      __hip_bfloat16* Cb = (__hip_bfloat16*)C;
      union { ushort4 u; __hip_bfloat16 b[4]; } p0, p1;
#pragma unroll
      for (int j = 0; j < 4; ++j) { p0.b[j] = __float2bfloat16(v0[j]); p1.b[j] = __float2bfloat16(v1[j]); }
      *(ushort4*)(Cb + (size_t)row * J + col0) = p0.u;
      *(ushort4*)(Cb + (size_t)row * J + col1) = p1.u;
    } else {
      *(float4*)(C + (size_t)row * J + col0) = *(float4*)v0;
      *(float4*)(C + (size_t)row * J + col1) = *(float4*)v1;
    }
  }
}

// ---------------------------------------------------------------------------
// GRU recurrence v4: MFMA-based. Grid (nseq/16, 2), 512 threads (8 waves).
// Block owns 16 seqs, dir d. Per step: H[16x128]@Whh_d^T[384x128] via MFMA,
// Whh bf16 fragments persistent in VGPRs (wave w owns cols w*48..w*48+47).
// gi: bf16 [nseq][L][768] (+d*384); whhb: bf16 [2][384][128]; out fp32
// [nseq][L][256] (+d*128).
// ---------------------------------------------------------------------------
__global__ __launch_bounds__(512) void k_gru4(const __hip_bfloat16* __restrict__ gi,
                                              const __hip_bfloat16* __restrict__ whhb,
                                              const float* __restrict__ bhh,
                                              float* __restrict__ out,
                                              int L) {
  __shared__ __align__(16) __hip_bfloat16 hsb[16][136];  // pad: 2-way alias only
  __shared__ float outl[16][392];                        // 384 + 8 pad
  int tid = threadIdx.x;
  int d = blockIdx.y;
  int n0 = blockIdx.x * 16;
  int w = tid >> 6, lane = tid & 63;
  int fr = lane & 15;
  int kg = (lane >> 4) * 8;
  int jw = w * 48;

  // persistent B fragments (Whh), same lane-group->k mapping as A
  bf16x8v bfr[3][4];
  const __hip_bfloat16* wb = whhb + (size_t)d * 384 * 128;
#pragma unroll
  for (int cf = 0; cf < 3; ++cf)
#pragma unroll
    for (int kf = 0; kf < 4; ++kf)
      bfr[cf][kf] = *(const bf16x8v*)(wb + (size_t)(jw + cf * 16 + fr) * 128 + kf * 32 + kg);

  // gate-thread mapping: s = seq-local, j0 = 4 consecutive hidden units
  int s = tid >> 5;
  int j0 = (tid & 31) * 4;
  const float* bh = bhh + d * 384;
  float4 br = *(const float4*)(bh + j0);
  float4 bz = *(const float4*)(bh + 128 + j0);
  float4 bn = *(const float4*)(bh + 256 + j0);

  float h[4] = {0.f, 0.f, 0.f, 0.f};
  for (int i = tid; i < 16 * 136; i += 512) ((__hip_bfloat16*)hsb)[i] = __float2bfloat16(0.f);
  __syncthreads();

  int t = d ? (L - 1) : 0;
  int dt = d ? -1 : 1;

  for (int step = 0; step < L; ++step, t += dt) {
    // prefetch gi for this step (used after the mid barrier)
    const __hip_bfloat16* g = gi + (size_t)((n0 + s) * L + t) * 768 + d * 384 + j0;
    ushort4 gr4 = *(const ushort4*)(g);
    ushort4 gz4 = *(const ushort4*)(g + 128);
    ushort4 gn4 = *(const ushort4*)(g + 256);

    // MFMA phase: acc[cf] over K=128 (4 k-frags)
    f32x4 acc[3];
#pragma unroll
    for (int cf = 0; cf < 3; ++cf) acc[cf] = (f32x4){0.f, 0.f, 0.f, 0.f};
#pragma unroll
    for (int kf = 0; kf < 4; ++kf) {
      bf16x8v a = *(const bf16x8v*)(&hsb[fr][kf * 32 + kg]);
#pragma unroll
      for (int cf = 0; cf < 3; ++cf)
        acc[cf] = __builtin_amdgcn_mfma_f32_16x16x32_bf16(a, bfr[cf][kf], acc[cf], 0, 0, 0);
    }
    int r0 = (lane >> 4) * 4;
#pragma unroll
    for (int cf = 0; cf < 3; ++cf) {
      int col = jw + cf * 16 + fr;
#pragma unroll
      for (int r = 0; r < 4; ++r) outl[r0 + r][col] = acc[cf][r];
    }
    __syncthreads();

    // gate phase
    float4 sr = *(const float4*)&outl[s][j0];
    float4 sz = *(const float4*)&outl[s][128 + j0];
    float4 sn = *(const float4*)&outl[s][256 + j0];
    float gr[4] = {bu2f(gr4.x), bu2f(gr4.y), bu2f(gr4.z), bu2f(gr4.w)};
    float gz[4] = {bu2f(gz4.x), bu2f(gz4.y), bu2f(gz4.z), bu2f(gz4.w)};
    float gn[4] = {bu2f(gn4.x), bu2f(gn4.y), bu2f(gn4.z), bu2f(gn4.w)};
    float srv[4] = {sr.x, sr.y, sr.z, sr.w};
    float szv[4] = {sz.x, sz.y, sz.z, sz.w};
    float snv[4] = {sn.x, sn.y, sn.z, sn.w};
    float brv[4] = {br.x, br.y, br.z, br.w};
    float bzv[4] = {bz.x, bz.y, bz.z, bz.w};
    float bnv[4] = {bn.x, bn.y, bn.z, bn.w};
#pragma unroll
    for (int j = 0; j < 4; ++j) {
      float r = sigf(gr[j] + srv[j] + brv[j]);
      float z = sigf(gz[j] + szv[j] + bzv[j]);
      float nn = tanhf(gn[j] + r * (snv[j] + bnv[j]));
      h[j] = (1.f - z) * nn + z * h[j];
    }
    *(float4*)(out + (size_t)((n0 + s) * L + t) * 256 + d * 128 + j0) =
        (float4){h[0], h[1], h[2], h[3]};
    union { ushort4 u; __hip_bfloat16 b[4]; } hp;
#pragma unroll
    for (int j = 0; j < 4; ++j) hp.b[j] = __float2bfloat16(h[j]);
    *(ushort4*)&hsb[s][j0] = hp.u;
    __syncthreads();
  }
}

// ---------------------------------------------------------------------------
// Attention pool (one block per n)
// ---------------------------------------------------------------------------
__global__ __launch_bounds__(256) void k_attn_pool(const float* __restrict__ score_src,
                                                   int s_ns, int s_ls,
                                                   const float* __restrict__ val_src,
                                                   int v_ns, int v_ls,
                                                   const float* __restrict__ w,
                                                   const float* __restrict__ bptr,
                                                   float* __restrict__ dst,
                                                   int dst_stride, int L) {
  __shared__ float wts[64];
  int n = blockIdx.x;
  int tid = threadIdx.x;
  if (tid < 64) {
    float a = -INFINITY;
    if (tid < L) {
      const float* row = score_src + (size_t)n * s_ns + (size_t)tid * s_ls;
      float s = bptr[0];
      for (int h = 0; h < 256; h += 4) {
        float4 v = *(const float4*)(row + h);
        float4 wv = *(const float4*)(w + h);
        s += v.x * wv.x + v.y * wv.y + v.z * wv.z + v.w * wv.w;
      }
      a = s;
    }
    float mx = a;
#pragma unroll
    for (int off = 32; off; off >>= 1) mx = fmaxf(mx, __shfl_xor(mx, off));
    float e = (tid < L) ? expf(a - mx) : 0.f;
    float ss = e;
#pragma unroll
    for (int off = 32; off; off >>= 1) ss += __shfl_xor(ss, off);
    if (tid < L) wts[tid] = e / ss;
  }
  __syncthreads();
  float acc = 0.f;
  for (int l = 0; l < L; ++l)
    acc += wts[l] * val_src[(size_t)n * v_ns + (size_t)l * v_ls + tid];
  dst[(size_t)n * dst_stride + tid] = acc;
}

// ---------------------------------------------------------------------------
// xn[n][m][h] = 0.5*label_tab[lbl][h] + (1/16)*sum_t tok_tab[id][h]  (bf16 out)
// ---------------------------------------------------------------------------
__global__ __launch_bounds__(256) void k_xn_bf16(const float* __restrict__ label_tab,
                                                 const float* __restrict__ tok_tab,
                                                 const int* __restrict__ lbl_ids,
                                                 const int* __restrict__ tok_ids,
                                                 __hip_bfloat16* __restrict__ xnb) {
  int nm = blockIdx.x;
  int h = threadIdx.x;
  const int* tids = tok_ids + (size_t)nm * 8;
  float s = 0.f;
#pragma unroll
  for (int t = 0; t < 8; ++t) s += tok_tab[(size_t)tids[t] * 256 + h];
  float v = 0.5f * label_tab[(size_t)lbl_ids[nm] * 256 + h] + 0.0625f * s;
  xnb[(size_t)nm * 256 + h] = __float2bfloat16(v);
}

// ---------------------------------------------------------------------------
// TreeLSTM combine (step m): gates from bf16 XWALL + gathered bf16 HU.
// Dual-writes h as bf16 (HBF) for the MFMA projection.
// ---------------------------------------------------------------------------
__global__ __launch_bounds__(256) void k_tl_combine4(const __hip_bfloat16* __restrict__ HU,
                                                     const __hip_bfloat16* __restrict__ XWALL,
                                                     const int* __restrict__ ch,
                                                     const int* __restrict__ msk,
                                                     float* __restrict__ h_arr,
                                                     float* __restrict__ c_arr,
                                                     __hip_bfloat16* __restrict__ hbf,
                                                     int m) {
  int n = blockIdx.x, h = threadIdx.x;
  const __hip_bfloat16* xw = XWALL + ((size_t)(n * 64 + m)) * 1024;
  float si = b2f(xw[h]), so = b2f(xw[256 + h]), su = b2f(xw[512 + h]);
  float xfv = b2f(xw[768 + h]);
  const int* chp = ch + ((size_t)(n * 64 + m)) * 4;
  const int* mkp = msk + ((size_t)(n * 64 + m)) * 4;
  float cs = 0.f;
#pragma unroll
  for (int c = 0; c < 4; ++c) {
    if (mkp[c]) {
      int cc = chp[c];
      const __hip_bfloat16* hu = HU + ((size_t)cc * 512 + n) * 1024;
      si += b2f(hu[h]);
      so += b2f(hu[256 + h]);
      su += b2f(hu[512 + h]);
      float fg = sigf(xfv + b2f(hu[768 + h]));
      cs += fg * c_arr[((size_t)cc * 512 + n) * 256 + h];
    }
  }
  float iv = sigf(si), ov = sigf(so), uv = tanhf(su);
  float cn = iv * uv + cs;
  float hn = ov * tanhf(cn);
  h_arr[((size_t)m * 512 + n) * 256 + h] = hn;
  c_arr[((size_t)m * 512 + n) * 256 + h] = cn;
  hbf[(size_t)n * 256 + h] = __float2bfloat16(hn);
}

// ---------------------------------------------------------------------------
// Graph kernels
// ---------------------------------------------------------------------------
__global__ __launch_bounds__(256) void k_edge_deg(const int* __restrict__ edges,
                                                  int* __restrict__ deg, int E) {
  int i = blockIdx.x * 256 + threadIdx.x;
  if (i < E) {
    atomicAdd(&deg[edges[2 * i]], 1);
    atomicAdd(&deg[edges[2 * i + 1]], 1);
  }
}

__global__ __launch_bounds__(256) void k_nei(const int* __restrict__ edges,
                                             const float* __restrict__ x,
                                             float* __restrict__ nei_sum) {
  int e = blockIdx.x, h = threadIdx.x;
  int a = edges[2 * e], b = edges[2 * e + 1];
  atomicAdd(&nei_sum[(size_t)a * 256 + h], x[(size_t)b * 256 + h]);
  atomicAdd(&nei_sum[(size_t)b * 256 + h], x[(size_t)a * 256 + h]);
}

__global__ __launch_bounds__(256) void k_xcat(const float* __restrict__ x,
                                              const float* __restrict__ nei_sum,
                                              const int* __restrict__ deg,
                                              float* __restrict__ xcat) {
  int n = blockIdx.x, h = threadIdx.x;
  xcat[(size_t)n * 512 + h] = x[(size_t)n * 256 + h];
  float d = fmaxf((float)deg[n], 1.f);
  xcat[(size_t)n * 512 + 256 + h] = nei_sum[(size_t)n * 256 + h] / d;
}

__global__ __launch_bounds__(256) void k_spmm_self(const float* __restrict__ y,
                                                   const int* __restrict__ deg,
                                                   float* __restrict__ ob) {
  int n = blockIdx.x, h = threadIdx.x;
  float dis2 = 1.f / (float)(deg[n] + 1);
  ob[(size_t)n * 256 + h] = dis2 * y[(size_t)n * 256 + h];
}

__global__ __launch_bounds__(256) void k_spmm_edge(const float* __restrict__ y,
                                                   const int* __restrict__ deg,
                                                   const int* __restrict__ edges,
                                                   float* __restrict__ ob) {
  int e = blockIdx.x, h = threadIdx.x;
  int a = edges[2 * e], b = edges[2 * e + 1];
  float w = (1.f / sqrtf((float)(deg[a] + 1))) * (1.f / sqrtf((float)(deg[b] + 1)));
  atomicAdd(&ob[(size_t)a * 256 + h], w * y[(size_t)b * 256 + h]);
  atomicAdd(&ob[(size_t)b * 256 + h], w * y[(size_t)a * 256 + h]);
}

__global__ __launch_bounds__(256) void k_relu_inplace(float* __restrict__ p) {
  int i = blockIdx.x * 256 + threadIdx.x;
  p[i] = fmaxf(p[i], 0.f);
}

__global__ __launch_bounds__(256) void k_final(const float* __restrict__ h2,
                                               const float* __restrict__ w1,
                                               const float* __restrict__ b1,
                                               const float* __restrict__ w2,
                                               const float* __restrict__ b2,
                                               float* __restrict__ outp) {
  __shared__ float gv[512];
  __shared__ float zz[256];
  int tid = threadIdx.x;
  float mn = 0.f, mx = -INFINITY;
  for (int n = 0; n < 512; ++n) {
    float v = h2[(size_t)n * 256 + tid];
    mn += v;
    mx = fmaxf(mx, v);
  }
  gv[tid] = mn / 512.f;
  gv[256 + tid] = mx;
  __syncthreads();
  float acc = b1[tid];
  for (int k = 0; k < 512; ++k) acc += gv[k] * w1[(size_t)tid * 512 + k];
  zz[tid] = fmaxf(acc, 0.f) * w2[tid];
  __syncthreads();
  for (int s = 128; s; s >>= 1) {
    if (tid < s) zz[tid] += zz[tid + s];
    __syncthreads();
  }
  if (tid == 0) outp[0] = zz[0] + b2[0];
}

// ---------------------------------------------------------------------------
// Host launch
// ---------------------------------------------------------------------------
extern "C" void kernel_launch(void* const* d_in, const int* in_sizes, int n_in,
                              void* d_out, int out_size, void* d_ws, size_t ws_size,
                              hipStream_t stream) {
  const int* seq_tokens    = (const int*)d_in[0];
  const int* ast_children  = (const int*)d_in[1];
  const void* ast_mask_raw = (const void*)d_in[2];
  const int* ast_label_ids = (const int*)d_in[3];
  const int* ast_tok_ids   = (const int*)d_in[4];
  const int* ctx_nei       = (const int*)d_in[5];
  const int* edges         = (const int*)d_in[6];
  const float* seq_emb  = (const float*)d_in[7];
  const float* seq_wih  = (const float*)d_in[8];
  const float* seq_whh  = (const float*)d_in[9];
  const float* seq_bih  = (const float*)d_in[10];
  const float* seq_bhh  = (const float*)d_in[11];
  const float* seq_pw   = (const float*)d_in[12];
  const float* seq_pb   = (const float*)d_in[13];
  const float* ctx_wih  = (const float*)d_in[14];
  const float* ctx_whh  = (const float*)d_in[15];
  const float* ctx_bih  = (const float*)d_in[16];
  const float* ctx_bhh  = (const float*)d_in[17];
  const float* ctx_pw   = (const float*)d_in[18];
  const float* ctx_pb   = (const float*)d_in[19];
  const float* ast_label_tab = (const float*)d_in[20];
  const float* ast_tok_tab   = (const float*)d_in[21];
  const float* ast_pw   = (const float*)d_in[22];
  const float* ast_pb   = (const float*)d_in[23];
  const float* tl_wiou  = (const float*)d_in[24];
  const float* tl_biou  = (const float*)d_in[25];
  const float* tl_uiou  = (const float*)d_in[26];
  const float* tl_wf    = (const float*)d_in[27];
  const float* tl_bf    = (const float*)d_in[28];
  const float* tl_uf    = (const float*)d_in[29];
  const float* fa_wih   = (const float*)d_in[30];
  const float* fa_whh   = (const float*)d_in[31];
  const float* fa_bih   = (const float*)d_in[32];
  const float* fa_bhh   = (const float*)d_in[33];
  const float* fa_aw    = (const float*)d_in[34];
  const float* fa_ab    = (const float*)d_in[35];
  const float* comb_w   = (const float*)d_in[36];
  const float* comb_b   = (const float*)d_in[37];
  const float* g1_w     = (const float*)d_in[38];
  const float* g1_b     = (const float*)d_in[39];
  const float* g2_w     = (const float*)d_in[40];
  const float* g2_b     = (const float*)d_in[41];
  const float* cls_w1   = (const float*)d_in[42];
  const float* cls_b1   = (const float*)d_in[43];
  const float* cls_w2   = (const float*)d_in[44];
  const float* cls_b2   = (const float*)d_in[45];
  float* outp = (float*)d_out;
  float* ws = (float*)d_ws;
  int E = in_sizes[6] / 2;

  // ----- workspace layout (floats) -----
  size_t off = 0;
  auto take = [&](size_t n) { size_t o = off; off += n; return o; };
  const size_t F_FEATS = take(512 * 5 * 256);
  const size_t F_X     = take(512 * 256);
  const size_t F_X2    = take(512 * 256);
  const size_t F_Y     = take(512 * 256);
  const size_t F_H1    = take(512 * 256);
  const size_t F_H2    = take(512 * 256);
  const size_t F_XCAT  = take(512 * 512);
  const size_t F_NEI   = take(512 * 256);
  const size_t F_DEG   = take(512);
  const size_t F_FLAG  = take(16);
  const size_t F_MSK   = take(512 * 64 * 4);
  const size_t F_WXW   = take(1024 * 256);
  const size_t F_WXB   = take(1024);
  const size_t F_WPROJ = take(1024 * 256);
  const size_t F_REGION = take(83886080);  // shared phase region
  (void)ws_size;

  float* FEATS = ws + F_FEATS;
  float* X     = ws + F_X;
  float* X2    = ws + F_X2;
  float* Y     = ws + F_Y;
  float* H1    = ws + F_H1;
  float* H2    = ws + F_H2;
  float* XCAT  = ws + F_XCAT;
  float* NEI   = ws + F_NEI;
  int*   DEG   = (int*)(ws + F_DEG);
  int*   FLAG  = (int*)(ws + F_FLAG);
  int*   MSK   = (int*)(ws + F_MSK);
  float* WXW   = ws + F_WXW;
  float* WXB   = ws + F_WXB;
  float* WPROJ = ws + F_WPROJ;
  float* REG   = ws + F_REGION;
  // enc/ctx phase
  __hip_bfloat16* GI16  = (__hip_bfloat16*)REG;             // 32768x768 bf16
  float* OUT   = REG + 13631488;                            // 8.39M fp32
  // TL phase
  __hip_bfloat16* XWALL16 = (__hip_bfloat16*)REG;           // 32768x1024 bf16
  float* HARR  = REG + 17000000;                            // 8.39M
  float* CARR  = REG + 25500000;                            // 8.39M
  __hip_bfloat16* HU16 = (__hip_bfloat16*)(REG + 34000000); // 64x512x1024 bf16
  // fa phase
  __hip_bfloat16* GIFA16 = (__hip_bfloat16*)REG;            // 2560x768 bf16
  float* OUTFA = REG + 1966080;
  // bf16 MFMA scratch (above all per-phase regions; [60M, 83.9M) is free in
  // every phase)
  __hip_bfloat16* ABF     = (__hip_bfloat16*)(REG + 60000000); // 32768x256 bf16
  __hip_bfloat16* WSEQBF  = (__hip_bfloat16*)(REG + 65000000); // 2304x256
  __hip_bfloat16* WCTXBF  = (__hip_bfloat16*)(REG + 65400000); // 768x256
  __hip_bfloat16* WFABF   = (__hip_bfloat16*)(REG + 65600000); // 768x256
  __hip_bfloat16* WXWBF   = (__hip_bfloat16*)(REG + 65800000); // 1024x256
  __hip_bfloat16* WPROJBF = (__hip_bfloat16*)(REG + 66100000); // 1024x256
  __hip_bfloat16* HBF     = (__hip_bfloat16*)(REG + 66500000); // 512x256
  __hip_bfloat16* WHHSEQBF = (__hip_bfloat16*)(REG + 66600000); // 3x2x384x128
  __hip_bfloat16* WHHCTXBF = (__hip_bfloat16*)(REG + 66800000); // 2x384x128
  __hip_bfloat16* WHHFABF  = (__hip_bfloat16*)(REG + 66900000); // 2x384x128

  auto gemm = [&](const float* A, const int* ridx, int rstride, const float* W,
                  const float* bias, float* C, int R, int K, int J, int relu,
                  int obf) {
    dim3 g((R / 128) * (J / 128));
    k_gemm128<<<g, 256, 0, stream>>>(A, ridx, rstride, W, bias, C, R, K, J, relu, obf);
  };
  auto cvt = [&](const float* A, const int* ridx, int rstride,
                 __hip_bfloat16* ob, int R) {
    k_cvt_bf16<<<R / 8, 256, 0, stream>>>(A, ridx, rstride, ob);
  };
  auto mgemm = [&](const __hip_bfloat16* A, const __hip_bfloat16* W,
                   const float* bias, void* C, int R, int K, int J, int relu,
                   int obf) {
    dim3 g((R / 128) * (J / 128));
    k_gemm_mfma<<<g, 256, 0, stream>>>(A, W, bias, C, R, K, J, relu, obf);
  };

  // ---- prep ----
  k_build_wx<<<1024, 256, 0, stream>>>(tl_wiou, tl_wf, tl_biou, tl_bf, WXW, WXB);
  k_build_wproj<<<1024, 256, 0, stream>>>(tl_uiou, tl_uf, WPROJ);
  k_zero_misc<<<512, 256, 0, stream>>>(NEI, DEG, FLAG);
  k_mask_detect<<<128, 256, 0, stream>>>((const unsigned*)ast_mask_raw, FLAG);
  k_mask_convert<<<512, 256, 0, stream>>>(ast_mask_raw, FLAG, MSK);
  // weight panels -> bf16 (once per launch)
  cvt(seq_wih, nullptr, 256, WSEQBF, 2304);
  cvt(ctx_wih, nullptr, 256, WCTXBF, 768);
  cvt(fa_wih, nullptr, 256, WFABF, 768);
  cvt(WXW, nullptr, 256, WXWBF, 1024);
  cvt(WPROJ, nullptr, 256, WPROJBF, 1024);
  // recurrent weights -> bf16 (viewed as rows of 256 floats)
  cvt(seq_whh, nullptr, 256, WHHSEQBF, 1152);  // 3*2*384*128 = 1152*256
  cvt(ctx_whh, nullptr, 256, WHHCTXBF, 384);   // 2*384*128 = 384*256
  cvt(fa_whh, nullptr, 256, WHHFABF, 384);

  // ---- 3 sequence encoders: slots 0 (stmt), 2 (varn), 3 (vart) ----
  const int slot_of[3] = {0, 2, 3};
  for (int e = 0; e < 3; ++e) {
    cvt(seq_emb + (size_t)e * 50000 * 256, seq_tokens + (size_t)e * 32768, 256,
        ABF, 32768);
    mgemm(ABF, WSEQBF + (size_t)e * 768 * 256, seq_bih + (size_t)e * 768,
          GI16, 32768, 256, 768, 0, 1);
    k_gru4<<<dim3(32, 2), 512, 0, stream>>>(GI16, WHHSEQBF + (size_t)e * 2 * 384 * 128,
                                            seq_bhh + (size_t)e * 768, OUT, 64);
    k_attn_pool<<<512, 256, 0, stream>>>(OUT, 64 * 256, 256, OUT, 64 * 256, 256,
                                         seq_pw + e * 256, seq_pb + e,
                                         FEATS + slot_of[e] * 256, 1280, 64);
  }

  // ---- ctx encoder (needs stmt slot0): slot 4 ----
  cvt(FEATS, ctx_nei, 1280, ABF, 4096);
  mgemm(ABF, WCTXBF, ctx_bih, GI16, 4096, 256, 768, 0, 1);
  k_gru4<<<dim3(32, 2), 512, 0, stream>>>(GI16, WHHCTXBF, ctx_bhh, OUT, 8);
  k_attn_pool<<<512, 256, 0, stream>>>(OUT, 8 * 256, 256, OUT, 8 * 256, 256,
                                       ctx_pw, ctx_pb, FEATS + 4 * 256, 1280, 8);

  // ---- AST TreeLSTM: slot 1 ----
  k_xn_bf16<<<32768, 256, 0, stream>>>(ast_label_tab, ast_tok_tab, ast_label_ids,
                                       ast_tok_ids, ABF);
  mgemm(ABF, WXWBF, WXB, XWALL16, 32768, 256, 1024, 0, 1);
  for (int m = 0; m < 64; ++m) {
    k_tl_combine4<<<512, 256, 0, stream>>>(HU16, XWALL16, ast_children, MSK,
                                           HARR, CARR, HBF, m);
    if (m < 63)
      mgemm(HBF, WPROJBF, nullptr, HU16 + (size_t)m * 512 * 1024,
            512, 256, 1024, 0, 1);
  }
  k_attn_pool<<<512, 256, 0, stream>>>(HARR, 256, 512 * 256, HARR, 256, 512 * 256,
                                       ast_pw, ast_pb, FEATS + 1 * 256, 1280, 64);

  // ---- feature-attention biGRU over the 5 slots -> x ----
  cvt(FEATS, nullptr, 256, ABF, 2560);
  mgemm(ABF, WFABF, fa_bih, GIFA16, 2560, 256, 768, 0, 1);
  k_gru4<<<dim3(32, 2), 512, 0, stream>>>(GIFA16, WHHFABF, fa_bhh, OUTFA, 5);
  k_attn_pool<<<512, 256, 0, stream>>>(OUTFA, 5 * 256, 256, FEATS, 1280, 256,
                                       fa_aw, fa_ab, X, 256, 5);

  // ---- graph section ----
  k_edge_deg<<<(E + 255) / 256, 256, 0, stream>>>(edges, DEG, E);
  k_nei<<<E, 256, 0, stream>>>(edges, X, NEI);
  k_xcat<<<512, 256, 0, stream>>>(X, NEI, DEG, XCAT);
  gemm(XCAT, nullptr, 512, comb_w, comb_b, X2, 512, 512, 256, 1, 0);
  gemm(X2, nullptr, 256, g1_w, g1_b, Y, 512, 256, 256, 0, 0);
  k_spmm_self<<<512, 256, 0, stream>>>(Y, DEG, H1);
  k_spmm_edge<<<E, 256, 0, stream>>>(Y, DEG, edges, H1);
  k_relu_inplace<<<512, 256, 0, stream>>>(H1);
  gemm(H1, nullptr, 256, g2_w, g2_b, Y, 512, 256, 256, 0, 0);
  k_spmm_self<<<512, 256, 0, stream>>>(Y, DEG, H2);
  k_spmm_edge<<<E, 256, 0, stream>>>(Y, DEG, edges, H2);
  k_relu_inplace<<<512, 256, 0, stream>>>(H2);
  k_final<<<1, 256, 0, stream>>>(H2, cls_w1, cls_b1, cls_w2, cls_b2, outp);
}

// Round 4
// 1838.065 us; speedup vs baseline: 1.5715x; 1.1429x over previous
//
#include <hip/hip_runtime.h>
#include <hip/hip_bf16.h>
#include <cmath>

// ---------------------------------------------------------------------------
// Model dims: H=256 HID=128 V=50000 LV=200 N=512 L=64 M=64 C=4 T=8 K=8
// NOTE (round 5 lesson): cooperative grid.sync() costs ~37us on MI355X —
// never use it for a 126-sync loop; per-step kernel launches (~2-3us) win.
// NOTE (round 6): big GEMMs on bf16 MFMA (m97-style 128x128 tile).
// NOTE (round 7/8): GRU on MFMA, Whh persistent in VGPRs as bf16 frags.
// NOTE (round 9): k_gru4 was latency-bound (4500 cyc/step: MfmaUtil 2%,
// VALUBusy 13%, Occ 5.5%). Fixes: (a) batch the 3 independent seq encoders
// into ONE launch (grid 96x2 — 3x parallelism, same serial depth);
// (b) raw s_barrier + lgkmcnt(0) instead of __syncthreads (which drains
// vmcnt(0)) so next-step gi prefetch stays in flight across barriers;
// (c) fast gates via v_exp_f32/v_rcp_f32 (__expf + rcp, clamped-tanh
// identity) instead of libm; (d) outl stride 392->396 (4-way -> 2-way
// LDS write conflict).
// ---------------------------------------------------------------------------

__device__ __forceinline__ float sigf(float x) { return 1.f / (1.f + expf(-x)); }
__device__ __forceinline__ float b2f(__hip_bfloat16 x) { return __bfloat162float(x); }
__device__ __forceinline__ float bu2f(unsigned short u) {
  union { float f; unsigned i; } v; v.i = ((unsigned)u) << 16; return v.f;
}
// fast gate math: v_exp_f32 + v_rcp_f32 (~1ulp; negligible vs bf16 inputs)
__device__ __forceinline__ float fsig(float x) {
  return __builtin_amdgcn_rcpf(1.f + __expf(-x));
}
__device__ __forceinline__ float ftanh(float x) {
  float cx = fminf(fmaxf(x, -15.f), 15.f);
  float e = __expf(2.f * cx);
  return 1.f - 2.f * __builtin_amdgcn_rcpf(e + 1.f);
}

typedef __attribute__((ext_vector_type(8))) short bf16x8v;  // 8 bf16 (4 VGPRs)
typedef __attribute__((ext_vector_type(4))) float f32x4;

__device__ __forceinline__ void gload16(const __hip_bfloat16* g, __hip_bfloat16* l) {
  __builtin_amdgcn_global_load_lds((const __attribute__((address_space(1))) void*)g,
                                   (__attribute__((address_space(3))) void*)l, 16, 0, 0);
}

// LDS-only barrier: wait own ds ops, then raw s_barrier. Does NOT drain
// vmcnt, so global-load prefetches stay in flight across it.
__device__ __forceinline__ void lds_barrier() {
  asm volatile("s_waitcnt lgkmcnt(0)" ::: "memory");
  __builtin_amdgcn_sched_barrier(0);
  __builtin_amdgcn_s_barrier();
}

// ---------------------------------------------------------------------------
// WXALL weights: [wiou (768) | wf (256)] rows x 256, bias [biou | bf]
// ---------------------------------------------------------------------------
__global__ __launch_bounds__(256) void k_build_wx(const float* __restrict__ wiou,
                                                  const float* __restrict__ wf,
                                                  const float* __restrict__ biou,
                                                  const float* __restrict__ bf,
                                                  float* __restrict__ w,
                                                  float* __restrict__ b) {
  int i = blockIdx.x * 256 + threadIdx.x;
  if (i < 1024 * 256) {
    int j = i >> 8, k = i & 255;
    w[i] = (j < 768) ? wiou[j * 256 + k] : wf[(j - 768) * 256 + k];
  }
  if (i < 1024) b[i] = (i < 768) ? biou[i] : bf[i - 768];
}

// WPROJ: [uiou (768) | uf (256)] rows x 256
__global__ __launch_bounds__(256) void k_build_wproj(const float* __restrict__ uiou,
                                                     const float* __restrict__ uf,
                                                     float* __restrict__ w) {
  int i = blockIdx.x * 256 + threadIdx.x;
  if (i >= 1024 * 256) return;
  int j = i >> 8, k = i & 255;
  w[i] = (j < 768) ? uiou[j * 256 + k] : uf[(j - 768) * 256 + k];
}

__global__ __launch_bounds__(256) void k_zero_misc(float* __restrict__ nei_sum,
                                                   int* __restrict__ deg,
                                                   int* __restrict__ flag) {
  int i = blockIdx.x * 256 + threadIdx.x;
  if (i < 512 * 256) nei_sum[i] = 0.f;
  if (i < 512) deg[i] = 0;
  if (i == 0) *flag = 0;
}

// bool-mask dtype detector (int32 vs byte-packed)
__global__ __launch_bounds__(256) void k_mask_detect(const unsigned* __restrict__ raw,
                                                     int* __restrict__ flag) {
  int i = blockIdx.x * 256 + threadIdx.x;
  if (i < 32768) {
    if (raw[i] > 1u) atomicOr(flag, 1);
  }
}

__global__ __launch_bounds__(256) void k_mask_convert(const void* __restrict__ raw,
                                                      const int* __restrict__ flag,
                                                      int* __restrict__ msk) {
  int i = blockIdx.x * 256 + threadIdx.x;
  if (i >= 512 * 64 * 4) return;
  int v;
  if (*flag) v = ((const unsigned char*)raw)[i] != 0;
  else       v = ((const int*)raw)[i] != 0;
  msk[i] = v;
}

// ---------------------------------------------------------------------------
// fp32 -> bf16 row gather/convert: out[r][0:256] = bf16(A[(ridx?ridx[r]:r)*rstride + 0:256])
// one block = 8 rows; K fixed at 256.
// ---------------------------------------------------------------------------
__global__ __launch_bounds__(256) void k_cvt_bf16(const float* __restrict__ A,
                                                  const int* __restrict__ ridx,
                                                  int rstride,
                                                  __hip_bfloat16* __restrict__ out) {
  int r = blockIdx.x * 8 + (threadIdx.x >> 5);
  int k = (threadIdx.x & 31) * 8;
  const float* src = A + (size_t)(ridx ? ridx[r] : r) * rstride + k;
  float4 v0 = *(const float4*)src;
  float4 v1 = *(const float4*)(src + 4);
  union { ushort4 u; __hip_bfloat16 b[4]; } p0, p1;
  p0.b[0] = __float2bfloat16(v0.x); p0.b[1] = __float2bfloat16(v0.y);
  p0.b[2] = __float2bfloat16(v0.z); p0.b[3] = __float2bfloat16(v0.w);
  p1.b[0] = __float2bfloat16(v1.x); p1.b[1] = __float2bfloat16(v1.y);
  p1.b[2] = __float2bfloat16(v1.z); p1.b[3] = __float2bfloat16(v1.w);
  __hip_bfloat16* dst = out + (size_t)r * 256 + k;
  *(ushort4*)dst = p0.u;
  *(ushort4*)(dst + 4) = p1.u;
}

// ---------------------------------------------------------------------------
// bf16 MFMA GEMM: C[R x J] = A[R x K] @ W[J x K]^T (+bias, relu opt).
// 128x128 tile, BK=32, 256 threads = 4 waves in 2x2, each wave 64x64 out
// (4x4 fragments of 16x16x32). global_load_lds width-16 staging, linear LDS.
// Requires R%128==0, J%128==0, K%32==0.
// ---------------------------------------------------------------------------
__global__ __launch_bounds__(256) void k_gemm_mfma(const __hip_bfloat16* __restrict__ A,
                                                   const __hip_bfloat16* __restrict__ W,
                                                   const float* __restrict__ bias,
                                                   void* __restrict__ Cv,
                                                   int R, int K, int J,
                                                   int relu, int out_bf16) {
  __shared__ __align__(16) __hip_bfloat16 As[128 * 32];
  __shared__ __align__(16) __hip_bfloat16 Bs[128 * 32];
  int njt = J >> 7;
  int rt = blockIdx.x / njt;
  int jt = blockIdx.x - rt * njt;
  int tid = threadIdx.x;
  int w = tid >> 6, lane = tid & 63;
  int wr = w >> 1, wc = w & 1;

  const __hip_bfloat16* ga = A + (size_t)(rt * 128 + w * 32 + (lane >> 2)) * K + (lane & 3) * 8;
  const __hip_bfloat16* gb = W + (size_t)(jt * 128 + w * 32 + (lane >> 2)) * K + (lane & 3) * 8;
  __hip_bfloat16* lA0 = As + w * 1024;   // 32 rows * 32 k
  __hip_bfloat16* lB0 = Bs + w * 1024;
  size_t gstep16 = (size_t)16 * K;

  f32x4 acc[4][4];
#pragma unroll
  for (int m = 0; m < 4; ++m)
#pragma unroll
    for (int n = 0; n < 4; ++n) acc[m][n] = (f32x4){0.f, 0.f, 0.f, 0.f};

  int fr = lane & 15;            // A-row / B-col within fragment
  int kg = (lane >> 4) * 8;      // k offset: SAME mapping for A and B
  const __hip_bfloat16* raA = As + (size_t)(wr * 64 + fr) * 32 + kg;
  const __hip_bfloat16* raB = Bs + (size_t)(wc * 64 + fr) * 32 + kg;

  for (int k0 = 0; k0 < K; k0 += 32) {
    __syncthreads();  // prior iter's ds_reads done before overwrite
    gload16(ga, lA0);
    gload16(ga + gstep16, lA0 + 512);
    gload16(gb, lB0);
    gload16(gb + gstep16, lB0 + 512);
    ga += 32; gb += 32;
    __syncthreads();  // compiler drains vmcnt before s_barrier -> LDS ready
    bf16x8v a[4], b[4];
#pragma unroll
    for (int m = 0; m < 4; ++m) a[m] = *(const bf16x8v*)(raA + m * 512);
#pragma unroll
    for (int n = 0; n < 4; ++n) b[n] = *(const bf16x8v*)(raB + n * 512);
#pragma unroll
    for (int m = 0; m < 4; ++m)
#pragma unroll
      for (int n = 0; n < 4; ++n)
        acc[m][n] = __builtin_amdgcn_mfma_f32_16x16x32_bf16(a[m], b[n], acc[m][n], 0, 0, 0);
  }

  // C/D layout (HW-verified m89/m91): col = lane&15, row = (lane>>4)*4 + reg
  int row0 = rt * 128 + wr * 64 + (lane >> 4) * 4;
  int col0 = jt * 128 + wc * 64 + fr;
#pragma unroll
  for (int n = 0; n < 4; ++n) {
    int col = col0 + n * 16;
    float bv = bias ? bias[col] : 0.f;
#pragma unroll
    for (int m = 0; m < 4; ++m) {
#pragma unroll
      for (int j = 0; j < 4; ++j) {
        float v = acc[m][n][j] + bv;
        if (relu) v = fmaxf(v, 0.f);
        size_t idx = (size_t)(row0 + m * 16 + j) * J + col;
        if (out_bf16) ((__hip_bfloat16*)Cv)[idx] = __float2bfloat16(v);
        else ((float*)Cv)[idx] = v;
      }
    }
  }
}

// ---------------------------------------------------------------------------
// Generic fp32 GEMM (kept for comb/g1/g2 small GEMMs with fp32 consumers)
// ---------------------------------------------------------------------------
__global__ __launch_bounds__(256) void k_gemm128(const float* __restrict__ A,
                                                 const int* __restrict__ ridx,
                                                 int rstride,
                                                 const float* __restrict__ W,
                                                 const float* __restrict__ bias,
                                                 float* __restrict__ C,
                                                 int R, int K, int J, int relu,
                                                 int out_bf16) {
  __shared__ float As[16][132];
  __shared__ float Ws[16][132];
  int njt = J >> 7;
  int rt = blockIdx.x / njt;
  int jt = blockIdx.x % njt;
  int tid = threadIdx.x;
  int tx = tid & 15, ty = tid >> 4;

  int row2 = tid >> 1;
  int kq = (tid & 1) * 4;
  int gr = rt * 128 + row2;
  const float* arow = A + (size_t)(ridx ? ridx[gr] : gr) * rstride;
  const float* wrow = W + (size_t)(jt * 128 + row2) * K;

  float acc[8][8];
#pragma unroll
  for (int i = 0; i < 8; ++i)
#pragma unroll
    for (int j = 0; j < 8; ++j) acc[i][j] = 0.f;

  for (int k0 = 0; k0 < K; k0 += 16) {
    float4 av0 = *(const float4*)(arow + k0 + kq);
    float4 av1 = *(const float4*)(arow + k0 + kq + 8);
    float4 wv0 = *(const float4*)(wrow + k0 + kq);
    float4 wv1 = *(const float4*)(wrow + k0 + kq + 8);
    __syncthreads();
    As[kq + 0][row2] = av0.x; As[kq + 1][row2] = av0.y;
    As[kq + 2][row2] = av0.z; As[kq + 3][row2] = av0.w;
    As[kq + 8][row2] = av1.x; As[kq + 9][row2] = av1.y;
    As[kq + 10][row2] = av1.z; As[kq + 11][row2] = av1.w;
    Ws[kq + 0][row2] = wv0.x; Ws[kq + 1][row2] = wv0.y;
    Ws[kq + 2][row2] = wv0.z; Ws[kq + 3][row2] = wv0.w;
    Ws[kq + 8][row2] = wv1.x; Ws[kq + 9][row2] = wv1.y;
    Ws[kq + 10][row2] = wv1.z; Ws[kq + 11][row2] = wv1.w;
    __syncthreads();
#pragma unroll
    for (int kk = 0; kk < 16; ++kk) {
      float a[8], b[8];
      *(float4*)&a[0] = *(const float4*)&As[kk][ty * 4];
      *(float4*)&a[4] = *(const float4*)&As[kk][64 + ty * 4];
      *(float4*)&b[0] = *(const float4*)&Ws[kk][tx * 4];
      *(float4*)&b[4] = *(const float4*)&Ws[kk][64 + tx * 4];
#pragma unroll
      for (int i = 0; i < 8; ++i)
#pragma unroll
        for (int j = 0; j < 8; ++j) acc[i][j] += a[i] * b[j];
    }
  }

  int col0 = jt * 128 + tx * 4;
  int col1 = jt * 128 + 64 + tx * 4;
  float b0[4], b1[4];
#pragma unroll
  for (int j = 0; j < 4; ++j) {
    b0[j] = bias ? bias[col0 + j] : 0.f;
    b1[j] = bias ? bias[col1 + j] : 0.f;
  }
#pragma unroll
  for (int i = 0; i < 8; ++i) {
    int row = rt * 128 + ((i < 4) ? (ty * 4 + i) : (64 + ty * 4 + i - 4));
    float v0[4], v1[4];
#pragma unroll
    for (int j = 0; j < 4; ++j) {
      float x0 = acc[i][j] + b0[j];
      float x1 = acc[i][j + 4] + b1[j];
      if (relu) { x0 = fmaxf(x0, 0.f); x1 = fmaxf(x1, 0.f); }
      v0[j] = x0; v1[j] = x1;
    }
    if (out_bf16) {
      __hip_bfloat16* Cb = (__hip_bfloat16*)C;
      union { ushort4 u; __hip_bfloat16 b[4]; } p0, p1;
#pragma unroll
      for (int j = 0; j < 4; ++j) { p0.b[j] = __float2bfloat16(v0[j]); p1.b[j] = __float2bfloat16(v1[j]); }
      *(ushort4*)(Cb + (size_t)row * J + col0) = p0.u;
      *(ushort4*)(Cb + (size_t)row * J + col1) = p1.u;
    } else {
      *(float4*)(C + (size_t)row * J + col0) = *(float4*)v0;
      *(float4*)(C + (size_t)row * J + col1) = *(float4*)v1;
    }
  }
}

// ---------------------------------------------------------------------------
// GRU recurrence v5: MFMA + raw-barrier pipeline. Grid (nenc*bpe, 2),
// 512 threads (8 waves). Block: encoder e = bx/bpe, seqs n0 = (bx%bpe)*16,
// dir d = by. Whh bf16 frags persistent in VGPRs (wave w: cols w*48..+47).
// Next-step gi prefetched to regs; raw s_barrier (no vmcnt drain) keeps the
// prefetch in flight across both per-step barriers. Fast gates (v_exp/v_rcp).
// ---------------------------------------------------------------------------
__global__ __launch_bounds__(512) void k_gru5(const __hip_bfloat16* __restrict__ gi,
                                              const __hip_bfloat16* __restrict__ whhb,
                                              const float* __restrict__ bhh,
                                              float* __restrict__ out,
                                              int L, int bpe,
                                              unsigned gi_se, unsigned whh_se,
                                              unsigned bhh_se, unsigned out_se) {
  __shared__ __align__(16) __hip_bfloat16 hsb[16][136];  // 2-way alias only
  __shared__ float outl[16][396];  // 396 % 32 == 12 -> 2-way on scalar writes
  int tid = threadIdx.x;
  int d = blockIdx.y;
  int e = blockIdx.x / bpe;
  int n0 = (blockIdx.x - e * bpe) * 16;
  gi += (size_t)e * gi_se;
  whhb += (size_t)e * whh_se;
  bhh += (size_t)e * bhh_se;
  out += (size_t)e * out_se;

  int w = tid >> 6, lane = tid & 63;
  int fr = lane & 15;
  int kg = (lane >> 4) * 8;
  int jw = w * 48;

  // persistent B fragments (Whh), same lane-group->k mapping as A
  bf16x8v bfr[3][4];
  const __hip_bfloat16* wb = whhb + (size_t)d * 384 * 128;
#pragma unroll
  for (int cf = 0; cf < 3; ++cf)
#pragma unroll
    for (int kf = 0; kf < 4; ++kf)
      bfr[cf][kf] = *(const bf16x8v*)(wb + (size_t)(jw + cf * 16 + fr) * 128 + kf * 32 + kg);

  // gate-thread mapping: s = seq-local, j0 = 4 consecutive hidden units
  int s = tid >> 5;
  int j0 = (tid & 31) * 4;
  const float* bh = bhh + d * 384;
  float4 br = *(const float4*)(bh + j0);
  float4 bz = *(const float4*)(bh + 128 + j0);
  float4 bn = *(const float4*)(bh + 256 + j0);

  float h[4] = {0.f, 0.f, 0.f, 0.f};
  for (int i = tid; i < 16 * 136; i += 512) ((__hip_bfloat16*)hsb)[i] = __float2bfloat16(0.f);
  __syncthreads();

  int t = d ? (L - 1) : 0;
  int dt = d ? -1 : 1;
  const __hip_bfloat16* gbase = gi + (size_t)(n0 + s) * L * 768 + d * 384 + j0;

  // prologue: load gi for step 0
  const __hip_bfloat16* g0 = gbase + (size_t)t * 768;
  ushort4 cr = *(const ushort4*)g0;
  ushort4 cz = *(const ushort4*)(g0 + 128);
  ushort4 cn4 = *(const ushort4*)(g0 + 256);

  for (int step = 0; step < L; ++step) {
    // issue next-step gi loads (in flight across both raw barriers)
    int tn = t + dt;
    tn = (tn < 0) ? 0 : ((tn >= L) ? (L - 1) : tn);
    const __hip_bfloat16* gn_ = gbase + (size_t)tn * 768;
    ushort4 nr = *(const ushort4*)gn_;
    ushort4 nz = *(const ushort4*)(gn_ + 128);
    ushort4 nn4 = *(const ushort4*)(gn_ + 256);

    // MFMA phase: acc[cf] over K=128 (4 k-frags)
    f32x4 acc[3];
#pragma unroll
    for (int cf = 0; cf < 3; ++cf) acc[cf] = (f32x4){0.f, 0.f, 0.f, 0.f};
#pragma unroll
    for (int kf = 0; kf < 4; ++kf) {
      bf16x8v a = *(const bf16x8v*)(&hsb[fr][kf * 32 + kg]);
#pragma unroll
      for (int cf = 0; cf < 3; ++cf)
        acc[cf] = __builtin_amdgcn_mfma_f32_16x16x32_bf16(a, bfr[cf][kf], acc[cf], 0, 0, 0);
    }
    int r0 = (lane >> 4) * 4;
#pragma unroll
    for (int cf = 0; cf < 3; ++cf) {
      int col = jw + cf * 16 + fr;
#pragma unroll
      for (int r = 0; r < 4; ++r) outl[r0 + r][col] = acc[cf][r];
    }
    lds_barrier();  // outl ready; MFMA hsb-reads retired

    // gate phase (uses THIS step's prefetched gi regs)
    float4 sr = *(const float4*)&outl[s][j0];
    float4 sz = *(const float4*)&outl[s][128 + j0];
    float4 sn = *(const float4*)&outl[s][256 + j0];
    float grv[4] = {bu2f(cr.x), bu2f(cr.y), bu2f(cr.z), bu2f(cr.w)};
    float gzv[4] = {bu2f(cz.x), bu2f(cz.y), bu2f(cz.z), bu2f(cz.w)};
    float gnv[4] = {bu2f(cn4.x), bu2f(cn4.y), bu2f(cn4.z), bu2f(cn4.w)};
    float srv[4] = {sr.x, sr.y, sr.z, sr.w};
    float szv[4] = {sz.x, sz.y, sz.z, sz.w};
    float snv[4] = {sn.x, sn.y, sn.z, sn.w};
    float brv[4] = {br.x, br.y, br.z, br.w};
    float bzv[4] = {bz.x, bz.y, bz.z, bz.w};
    float bnv[4] = {bn.x, bn.y, bn.z, bn.w};
#pragma unroll
    for (int j = 0; j < 4; ++j) {
      float r = fsig(grv[j] + srv[j] + brv[j]);
      float z = fsig(gzv[j] + szv[j] + bzv[j]);
      float nn = ftanh(gnv[j] + r * (snv[j] + bnv[j]));
      h[j] = (1.f - z) * nn + z * h[j];
    }
    *(float4*)(out + (size_t)((n0 + s) * L + t) * 256 + d * 128 + j0) =
        (float4){h[0], h[1], h[2], h[3]};
    union { ushort4 u; __hip_bfloat16 b[4]; } hp;
#pragma unroll
    for (int j = 0; j < 4; ++j) hp.b[j] = __float2bfloat16(h[j]);
    *(ushort4*)&hsb[s][j0] = hp.u;
    lds_barrier();  // hsb ready for next MFMA; outl free for overwrite

    cr = nr; cz = nz; cn4 = nn4;
    t += dt;
  }
}

// ---------------------------------------------------------------------------
// Attention pool (one block per n)
// ---------------------------------------------------------------------------
__global__ __launch_bounds__(256) void k_attn_pool(const float* __restrict__ score_src,
                                                   int s_ns, int s_ls,
                                                   const float* __restrict__ val_src,
                                                   int v_ns, int v_ls,
                                                   const float* __restrict__ w,
                                                   const float* __restrict__ bptr,
                                                   float* __restrict__ dst,
                                                   int dst_stride, int L) {
  __shared__ float wts[64];
  int n = blockIdx.x;
  int tid = threadIdx.x;
  if (tid < 64) {
    float a = -INFINITY;
    if (tid < L) {
      const float* row = score_src + (size_t)n * s_ns + (size_t)tid * s_ls;
      float s = bptr[0];
      for (int h = 0; h < 256; h += 4) {
        float4 v = *(const float4*)(row + h);
        float4 wv = *(const float4*)(w + h);
        s += v.x * wv.x + v.y * wv.y + v.z * wv.z + v.w * wv.w;
      }
      a = s;
    }
    float mx = a;
#pragma unroll
    for (int off = 32; off; off >>= 1) mx = fmaxf(mx, __shfl_xor(mx, off));
    float e = (tid < L) ? expf(a - mx) : 0.f;
    float ss = e;
#pragma unroll
    for (int off = 32; off; off >>= 1) ss += __shfl_xor(ss, off);
    if (tid < L) wts[tid] = e / ss;
  }
  __syncthreads();
  float acc = 0.f;
  for (int l = 0; l < L; ++l)
    acc += wts[l] * val_src[(size_t)n * v_ns + (size_t)l * v_ls + tid];
  dst[(size_t)n * dst_stride + tid] = acc;
}

// ---------------------------------------------------------------------------
// xn[n][m][h] = 0.5*label_tab[lbl][h] + (1/16)*sum_t tok_tab[id][h]  (bf16 out)
// ---------------------------------------------------------------------------
__global__ __launch_bounds__(256) void k_xn_bf16(const float* __restrict__ label_tab,
                                                 const float* __restrict__ tok_tab,
                                                 const int* __restrict__ lbl_ids,
                                                 const int* __restrict__ tok_ids,
                                                 __hip_bfloat16* __restrict__ xnb) {
  int nm = blockIdx.x;
  int h = threadIdx.x;
  const int* tids = tok_ids + (size_t)nm * 8;
  float s = 0.f;
#pragma unroll
  for (int t = 0; t < 8; ++t) s += tok_tab[(size_t)tids[t] * 256 + h];
  float v = 0.5f * label_tab[(size_t)lbl_ids[nm] * 256 + h] + 0.0625f * s;
  xnb[(size_t)nm * 256 + h] = __float2bfloat16(v);
}

// ---------------------------------------------------------------------------
// TreeLSTM combine (step m): gates from bf16 XWALL + gathered bf16 HU.
// Dual-writes h as bf16 (HBF) for the MFMA projection. Fast gates.
// ---------------------------------------------------------------------------
__global__ __launch_bounds__(256) void k_tl_combine4(const __hip_bfloat16* __restrict__ HU,
                                                     const __hip_bfloat16* __restrict__ XWALL,
                                                     const int* __restrict__ ch,
                                                     const int* __restrict__ msk,
                                                     float* __restrict__ h_arr,
                                                     float* __restrict__ c_arr,
                                                     __hip_bfloat16* __restrict__ hbf,
                                                     int m) {
  int n = blockIdx.x, h = threadIdx.x;
  const __hip_bfloat16* xw = XWALL + ((size_t)(n * 64 + m)) * 1024;
  float si = b2f(xw[h]), so = b2f(xw[256 + h]), su = b2f(xw[512 + h]);
  float xfv = b2f(xw[768 + h]);
  const int* chp = ch + ((size_t)(n * 64 + m)) * 4;
  const int* mkp = msk + ((size_t)(n * 64 + m)) * 4;
  float cs = 0.f;
#pragma unroll
  for (int c = 0; c < 4; ++c) {
    if (mkp[c]) {
      int cc = chp[c];
      const __hip_bfloat16* hu = HU + ((size_t)cc * 512 + n) * 1024;
      si += b2f(hu[h]);
      so += b2f(hu[256 + h]);
      su += b2f(hu[512 + h]);
      float fg = fsig(xfv + b2f(hu[768 + h]));
      cs += fg * c_arr[((size_t)cc * 512 + n) * 256 + h];
    }
  }
  float iv = fsig(si), ov = fsig(so), uv = ftanh(su);
  float cn = iv * uv + cs;
  float hn = ov * ftanh(cn);
  h_arr[((size_t)m * 512 + n) * 256 + h] = hn;
  c_arr[((size_t)m * 512 + n) * 256 + h] = cn;
  hbf[(size_t)n * 256 + h] = __float2bfloat16(hn);
}

// ---------------------------------------------------------------------------
// Graph kernels
// ---------------------------------------------------------------------------
__global__ __launch_bounds__(256) void k_edge_deg(const int* __restrict__ edges,
                                                  int* __restrict__ deg, int E) {
  int i = blockIdx.x * 256 + threadIdx.x;
  if (i < E) {
    atomicAdd(&deg[edges[2 * i]], 1);
    atomicAdd(&deg[edges[2 * i + 1]], 1);
  }
}

__global__ __launch_bounds__(256) void k_nei(const int* __restrict__ edges,
                                             const float* __restrict__ x,
                                             float* __restrict__ nei_sum) {
  int e = blockIdx.x, h = threadIdx.x;
  int a = edges[2 * e], b = edges[2 * e + 1];
  atomicAdd(&nei_sum[(size_t)a * 256 + h], x[(size_t)b * 256 + h]);
  atomicAdd(&nei_sum[(size_t)b * 256 + h], x[(size_t)a * 256 + h]);
}

__global__ __launch_bounds__(256) void k_xcat(const float* __restrict__ x,
                                              const float* __restrict__ nei_sum,
                                              const int* __restrict__ deg,
                                              float* __restrict__ xcat) {
  int n = blockIdx.x, h = threadIdx.x;
  xcat[(size_t)n * 512 + h] = x[(size_t)n * 256 + h];
  float d = fmaxf((float)deg[n], 1.f);
  xcat[(size_t)n * 512 + 256 + h] = nei_sum[(size_t)n * 256 + h] / d;
}

__global__ __launch_bounds__(256) void k_spmm_self(const float* __restrict__ y,
                                                   const int* __restrict__ deg,
                                                   float* __restrict__ ob) {
  int n = blockIdx.x, h = threadIdx.x;
  float dis2 = 1.f / (float)(deg[n] + 1);
  ob[(size_t)n * 256 + h] = dis2 * y[(size_t)n * 256 + h];
}

__global__ __launch_bounds__(256) void k_spmm_edge(const float* __restrict__ y,
                                                   const int* __restrict__ deg,
                                                   const int* __restrict__ edges,
                                                   float* __restrict__ ob) {
  int e = blockIdx.x, h = threadIdx.x;
  int a = edges[2 * e], b = edges[2 * e + 1];
  float w = (1.f / sqrtf((float)(deg[a] + 1))) * (1.f / sqrtf((float)(deg[b] + 1)));
  atomicAdd(&ob[(size_t)a * 256 + h], w * y[(size_t)b * 256 + h]);
  atomicAdd(&ob[(size_t)b * 256 + h], w * y[(size_t)a * 256 + h]);
}

__global__ __launch_bounds__(256) void k_relu_inplace(float* __restrict__ p) {
  int i = blockIdx.x * 256 + threadIdx.x;
  p[i] = fmaxf(p[i], 0.f);
}

__global__ __launch_bounds__(256) void k_final(const float* __restrict__ h2,
                                               const float* __restrict__ w1,
                                               const float* __restrict__ b1,
                                               const float* __restrict__ w2,
                                               const float* __restrict__ b2,
                                               float* __restrict__ outp) {
  __shared__ float gv[512];
  __shared__ float zz[256];
  int tid = threadIdx.x;
  float mn = 0.f, mx = -INFINITY;
  for (int n = 0; n < 512; ++n) {
    float v = h2[(size_t)n * 256 + tid];
    mn += v;
    mx = fmaxf(mx, v);
  }
  gv[tid] = mn / 512.f;
  gv[256 + tid] = mx;
  __syncthreads();
  float acc = b1[tid];
  for (int k = 0; k < 512; ++k) acc += gv[k] * w1[(size_t)tid * 512 + k];
  zz[tid] = fmaxf(acc, 0.f) * w2[tid];
  __syncthreads();
  for (int s = 128; s; s >>= 1) {
    if (tid < s) zz[tid] += zz[tid + s];
    __syncthreads();
  }
  if (tid == 0) outp[0] = zz[0] + b2[0];
}

// ---------------------------------------------------------------------------
// Host launch
// ---------------------------------------------------------------------------
extern "C" void kernel_launch(void* const* d_in, const int* in_sizes, int n_in,
                              void* d_out, int out_size, void* d_ws, size_t ws_size,
                              hipStream_t stream) {
  const int* seq_tokens    = (const int*)d_in[0];
  const int* ast_children  = (const int*)d_in[1];
  const void* ast_mask_raw = (const void*)d_in[2];
  const int* ast_label_ids = (const int*)d_in[3];
  const int* ast_tok_ids   = (const int*)d_in[4];
  const int* ctx_nei       = (const int*)d_in[5];
  const int* edges         = (const int*)d_in[6];
  const float* seq_emb  = (const float*)d_in[7];
  const float* seq_wih  = (const float*)d_in[8];
  const float* seq_whh  = (const float*)d_in[9];
  const float* seq_bih  = (const float*)d_in[10];
  const float* seq_bhh  = (const float*)d_in[11];
  const float* seq_pw   = (const float*)d_in[12];
  const float* seq_pb   = (const float*)d_in[13];
  const float* ctx_wih  = (const float*)d_in[14];
  const float* ctx_whh  = (const float*)d_in[15];
  const float* ctx_bih  = (const float*)d_in[16];
  const float* ctx_bhh  = (const float*)d_in[17];
  const float* ctx_pw   = (const float*)d_in[18];
  const float* ctx_pb   = (const float*)d_in[19];
  const float* ast_label_tab = (const float*)d_in[20];
  const float* ast_tok_tab   = (const float*)d_in[21];
  const float* ast_pw   = (const float*)d_in[22];
  const float* ast_pb   = (const float*)d_in[23];
  const float* tl_wiou  = (const float*)d_in[24];
  const float* tl_biou  = (const float*)d_in[25];
  const float* tl_uiou  = (const float*)d_in[26];
  const float* tl_wf    = (const float*)d_in[27];
  const float* tl_bf    = (const float*)d_in[28];
  const float* tl_uf    = (const float*)d_in[29];
  const float* fa_wih   = (const float*)d_in[30];
  const float* fa_whh   = (const float*)d_in[31];
  const float* fa_bih   = (const float*)d_in[32];
  const float* fa_bhh   = (const float*)d_in[33];
  const float* fa_aw    = (const float*)d_in[34];
  const float* fa_ab    = (const float*)d_in[35];
  const float* comb_w   = (const float*)d_in[36];
  const float* comb_b   = (const float*)d_in[37];
  const float* g1_w     = (const float*)d_in[38];
  const float* g1_b     = (const float*)d_in[39];
  const float* g2_w     = (const float*)d_in[40];
  const float* g2_b     = (const float*)d_in[41];
  const float* cls_w1   = (const float*)d_in[42];
  const float* cls_b1   = (const float*)d_in[43];
  const float* cls_w2   = (const float*)d_in[44];
  const float* cls_b2   = (const float*)d_in[45];
  float* outp = (float*)d_out;
  float* ws = (float*)d_ws;
  int E = in_sizes[6] / 2;

  // ----- workspace layout (floats) -----
  size_t off = 0;
  auto take = [&](size_t n) { size_t o = off; off += n; return o; };
  const size_t F_FEATS = take(512 * 5 * 256);
  const size_t F_X     = take(512 * 256);
  const size_t F_X2    = take(512 * 256);
  const size_t F_Y     = take(512 * 256);
  const size_t F_H1    = take(512 * 256);
  const size_t F_H2    = take(512 * 256);
  const size_t F_XCAT  = take(512 * 512);
  const size_t F_NEI   = take(512 * 256);
  const size_t F_DEG   = take(512);
  const size_t F_FLAG  = take(16);
  const size_t F_MSK   = take(512 * 64 * 4);
  const size_t F_WXW   = take(1024 * 256);
  const size_t F_WXB   = take(1024);
  const size_t F_WPROJ = take(1024 * 256);
  const size_t F_REGION = take(83886080);  // shared phase region
  (void)ws_size;

  float* FEATS = ws + F_FEATS;
  float* X     = ws + F_X;
  float* X2    = ws + F_X2;
  float* Y     = ws + F_Y;
  float* H1    = ws + F_H1;
  float* H2    = ws + F_H2;
  float* XCAT  = ws + F_XCAT;
  float* NEI   = ws + F_NEI;
  int*   DEG   = (int*)(ws + F_DEG);
  int*   FLAG  = (int*)(ws + F_FLAG);
  int*   MSK   = (int*)(ws + F_MSK);
  float* WXW   = ws + F_WXW;
  float* WXB   = ws + F_WXB;
  float* WPROJ = ws + F_WPROJ;
  float* REG   = ws + F_REGION;

  // ---- phase-region layout ----
  // enc phase:  GI3 bf16 [3][32768][768] @ [0, 37.75M f); OUT3 fp32 @ 38M
  //             (3 x 8.39M f -> ends 63.17M)
  // ctx phase:  GI @ base (1.57M f), OUT @ 38M
  // TL phase:   XWALL16 @ base (8.4M f), HARR @17M, CARR @25.5M,
  //             HU16 @34M (16.8M f -> ends 50.8M; OUT3 dead by then)
  // fa phase:   GIFA @ base, OUTFA @ 38M
  // scratch (live across all phases) @ 63.5M+
  __hip_bfloat16* GI3  = (__hip_bfloat16*)REG;
  float* OUT3 = REG + 38000000;
  __hip_bfloat16* XWALL16 = (__hip_bfloat16*)REG;
  float* HARR  = REG + 17000000;
  float* CARR  = REG + 25500000;
  __hip_bfloat16* HU16 = (__hip_bfloat16*)(REG + 34000000);
  __hip_bfloat16* GIFA16 = (__hip_bfloat16*)REG;
  float* OUTFA = OUT3;

  float* SCR = REG + 63500000;
  __hip_bfloat16* ABF      = (__hip_bfloat16*)(SCR);            // 32768x256 (4.2M f)
  __hip_bfloat16* WSEQBF   = (__hip_bfloat16*)(SCR + 4200000);  // 2304x256 (0.29M f)
  __hip_bfloat16* WCTXBF   = (__hip_bfloat16*)(SCR + 4500000);  // 768x256
  __hip_bfloat16* WFABF    = (__hip_bfloat16*)(SCR + 4600000);  // 768x256
  __hip_bfloat16* WXWBF    = (__hip_bfloat16*)(SCR + 4700000);  // 1024x256
  __hip_bfloat16* WPROJBF  = (__hip_bfloat16*)(SCR + 4850000);  // 1024x256
  __hip_bfloat16* HBF      = (__hip_bfloat16*)(SCR + 5000000);  // 512x256
  __hip_bfloat16* WHHSEQBF = (__hip_bfloat16*)(SCR + 5100000);  // 3x2x384x128
  __hip_bfloat16* WHHCTXBF = (__hip_bfloat16*)(SCR + 5260000);  // 2x384x128
  __hip_bfloat16* WHHFABF  = (__hip_bfloat16*)(SCR + 5320000);  // 2x384x128

  auto gemm = [&](const float* A, const int* ridx, int rstride, const float* W,
                  const float* bias, float* C, int R, int K, int J, int relu,
                  int obf) {
    dim3 g((R / 128) * (J / 128));
    k_gemm128<<<g, 256, 0, stream>>>(A, ridx, rstride, W, bias, C, R, K, J, relu, obf);
  };
  auto cvt = [&](const float* A, const int* ridx, int rstride,
                 __hip_bfloat16* ob, int R) {
    k_cvt_bf16<<<R / 8, 256, 0, stream>>>(A, ridx, rstride, ob);
  };
  auto mgemm = [&](const __hip_bfloat16* A, const __hip_bfloat16* W,
                   const float* bias, void* C, int R, int K, int J, int relu,
                   int obf) {
    dim3 g((R / 128) * (J / 128));
    k_gemm_mfma<<<g, 256, 0, stream>>>(A, W, bias, C, R, K, J, relu, obf);
  };

  // ---- prep ----
  k_build_wx<<<1024, 256, 0, stream>>>(tl_wiou, tl_wf, tl_biou, tl_bf, WXW, WXB);
  k_build_wproj<<<1024, 256, 0, stream>>>(tl_uiou, tl_uf, WPROJ);
  k_zero_misc<<<512, 256, 0, stream>>>(NEI, DEG, FLAG);
  k_mask_detect<<<128, 256, 0, stream>>>((const unsigned*)ast_mask_raw, FLAG);
  k_mask_convert<<<512, 256, 0, stream>>>(ast_mask_raw, FLAG, MSK);
  // weight panels -> bf16 (once per launch)
  cvt(seq_wih, nullptr, 256, WSEQBF, 2304);
  cvt(ctx_wih, nullptr, 256, WCTXBF, 768);
  cvt(fa_wih, nullptr, 256, WFABF, 768);
  cvt(WXW, nullptr, 256, WXWBF, 1024);
  cvt(WPROJ, nullptr, 256, WPROJBF, 1024);
  // recurrent weights -> bf16 (viewed as rows of 256 floats)
  cvt(seq_whh, nullptr, 256, WHHSEQBF, 1152);  // 3*2*384*128 = 1152*256
  cvt(ctx_whh, nullptr, 256, WHHCTXBF, 384);   // 2*384*128 = 384*256
  cvt(fa_whh, nullptr, 256, WHHFABF, 384);

  // ---- 3 sequence encoders, batched GRU: slots 0 (stmt), 2 (varn), 3 (vart)
  const int slot_of[3] = {0, 2, 3};
  for (int e = 0; e < 3; ++e) {
    cvt(seq_emb + (size_t)e * 50000 * 256, seq_tokens + (size_t)e * 32768, 256,
        ABF, 32768);
    mgemm(ABF, WSEQBF + (size_t)e * 768 * 256, seq_bih + (size_t)e * 768,
          GI3 + (size_t)e * 32768 * 768, 32768, 256, 768, 0, 1);
  }
  k_gru5<<<dim3(96, 2), 512, 0, stream>>>(GI3, WHHSEQBF, seq_bhh, OUT3, 64, 32,
                                          32768u * 768u, 2u * 384u * 128u, 768u,
                                          32768u * 256u);
  for (int e = 0; e < 3; ++e) {
    k_attn_pool<<<512, 256, 0, stream>>>(OUT3 + (size_t)e * 32768 * 256, 64 * 256, 256,
                                         OUT3 + (size_t)e * 32768 * 256, 64 * 256, 256,
                                         seq_pw + e * 256, seq_pb + e,
                                         FEATS + slot_of[e] * 256, 1280, 64);
  }

  // ---- ctx encoder (needs stmt slot0): slot 4 ----
  cvt(FEATS, ctx_nei, 1280, ABF, 4096);
  mgemm(ABF, WCTXBF, ctx_bih, GI3, 4096, 256, 768, 0, 1);
  k_gru5<<<dim3(32, 2), 512, 0, stream>>>(GI3, WHHCTXBF, ctx_bhh, OUT3, 8, 32,
                                          0, 0, 0, 0);
  k_attn_pool<<<512, 256, 0, stream>>>(OUT3, 8 * 256, 256, OUT3, 8 * 256, 256,
                                       ctx_pw, ctx_pb, FEATS + 4 * 256, 1280, 8);

  // ---- AST TreeLSTM: slot 1 ----
  k_xn_bf16<<<32768, 256, 0, stream>>>(ast_label_tab, ast_tok_tab, ast_label_ids,
                                       ast_tok_ids, ABF);
  mgemm(ABF, WXWBF, WXB, XWALL16, 32768, 256, 1024, 0, 1);
  for (int m = 0; m < 64; ++m) {
    k_tl_combine4<<<512, 256, 0, stream>>>(HU16, XWALL16, ast_children, MSK,
                                           HARR, CARR, HBF, m);
    if (m < 63)
      mgemm(HBF, WPROJBF, nullptr, HU16 + (size_t)m * 512 * 1024,
            512, 256, 1024, 0, 1);
  }
  k_attn_pool<<<512, 256, 0, stream>>>(HARR, 256, 512 * 256, HARR, 256, 512 * 256,
                                       ast_pw, ast_pb, FEATS + 1 * 256, 1280, 64);

  // ---- feature-attention biGRU over the 5 slots -> x ----
  cvt(FEATS, nullptr, 256, ABF, 2560);
  mgemm(ABF, WFABF, fa_bih, GIFA16, 2560, 256, 768, 0, 1);
  k_gru5<<<dim3(32, 2), 512, 0, stream>>>(GIFA16, WHHFABF, fa_bhh, OUTFA, 5, 32,
                                          0, 0, 0, 0);
  k_attn_pool<<<512, 256, 0, stream>>>(OUTFA, 5 * 256, 256, FEATS, 1280, 256,
                                       fa_aw, fa_ab, X, 256, 5);

  // ---- graph section ----
  k_edge_deg<<<(E + 255) / 256, 256, 0, stream>>>(edges, DEG, E);
  k_nei<<<E, 256, 0, stream>>>(edges, X, NEI);
  k_xcat<<<512, 256, 0, stream>>>(X, NEI, DEG, XCAT);
  gemm(XCAT, nullptr, 512, comb_w, comb_b, X2, 512, 512, 256, 1, 0);
  gemm(X2, nullptr, 256, g1_w, g1_b, Y, 512, 256, 256, 0, 0);
  k_spmm_self<<<512, 256, 0, stream>>>(Y, DEG, H1);
  k_spmm_edge<<<E, 256, 0, stream>>>(Y, DEG, edges, H1);
  k_relu_inplace<<<512, 256, 0, stream>>>(H1);
  gemm(H1, nullptr, 256, g2_w, g2_b, Y, 512, 256, 256, 0, 0);
  k_spmm_self<<<512, 256, 0, stream>>>(Y, DEG, H2);
  k_spmm_edge<<<E, 256, 0, stream>>>(Y, DEG, edges, H2);
  k_relu_inplace<<<512, 256, 0, stream>>>(H2);
  k_final<<<1, 256, 0, stream>>>(H2, cls_w1, cls_b1, cls_w2, cls_b2, outp);
}